// Round 3
// baseline (415.052 us; speedup 1.0000x reference)
//
#include <hip/hip_runtime.h>
#include <math.h>

#define T_SEQ 1024
#define C_DIM 2048
#define H_NUM 16
#define D_HEAD 128
#define BT 4096              // B*T rows
#define QKV_N 6144           // 3*C

typedef __bf16 bf16x8 __attribute__((ext_vector_type(8)));
typedef float f32x4 __attribute__((ext_vector_type(4)));
typedef unsigned short u16;
typedef unsigned int u32;

#define AS1C(p) ((const __attribute__((address_space(1))) void*)(p))
#define AS3(p)  ((__attribute__((address_space(3))) void*)(p))

__device__ __forceinline__ u16 f2bf(float f) {
    u32 u = __builtin_bit_cast(u32, f);
    u += 0x7fffu + ((u >> 16) & 1u);          // RNE
    return (u16)(u >> 16);
}
__device__ __forceinline__ void unpack8(uint4 u, float* f) {
    const u32 w0 = u.x, w1 = u.y, w2 = u.z, w3 = u.w;
    f[0] = __builtin_bit_cast(float, w0 << 16);
    f[1] = __builtin_bit_cast(float, w0 & 0xffff0000u);
    f[2] = __builtin_bit_cast(float, w1 << 16);
    f[3] = __builtin_bit_cast(float, w1 & 0xffff0000u);
    f[4] = __builtin_bit_cast(float, w2 << 16);
    f[5] = __builtin_bit_cast(float, w2 & 0xffff0000u);
    f[6] = __builtin_bit_cast(float, w3 << 16);
    f[7] = __builtin_bit_cast(float, w3 & 0xffff0000u);
}
__device__ __forceinline__ uint4 pack8(const float* f) {
    uint4 u;
    u.x = (u32)f2bf(f[0]) | ((u32)f2bf(f[1]) << 16);
    u.y = (u32)f2bf(f[2]) | ((u32)f2bf(f[3]) << 16);
    u.z = (u32)f2bf(f[4]) | ((u32)f2bf(f[5]) << 16);
    u.w = (u32)f2bf(f[6]) | ((u32)f2bf(f[7]) << 16);
    return u;
}

__device__ __forceinline__ void ph_barrier() {
    asm volatile("" ::: "memory");
    __builtin_amdgcn_s_barrier();
    asm volatile("" ::: "memory");
}
__device__ __forceinline__ void lgkm0() {
    asm volatile("s_waitcnt lgkmcnt(0)" ::: "memory");
    __builtin_amdgcn_sched_barrier(0);
}

// ---------------------------------------------------------------------------
// Elementwise fp32 -> bf16 cast (x -> xb).
// ---------------------------------------------------------------------------
__global__ __launch_bounds__(256) void cast_bf16(
    const float* __restrict__ in, u16* __restrict__ out)
{
    int i = blockIdx.x * 256 + threadIdx.x;
    float4 v = ((const float4*)in)[i];
    ushort4 o;
    o.x = f2bf(v.x); o.y = f2bf(v.y); o.z = f2bf(v.z); o.w = f2bf(v.w);
    ((ushort4*)out)[i] = o;
}

// ---------------------------------------------------------------------------
// fp32 [R][Cc] -> bf16 [Cc][R] transpose+cast. 32x32 tile, 256 threads.
// ---------------------------------------------------------------------------
__global__ __launch_bounds__(256) void transpose_cast(
    const float* __restrict__ in, u16* __restrict__ out, int R, int Cc)
{
    __shared__ float tile[32][33];
    const int c0 = blockIdx.x * 32, r0 = blockIdx.y * 32;
    const int tx = threadIdx.x & 31, ty = threadIdx.x >> 5;  // ty 0..7
#pragma unroll
    for (int i = 0; i < 32; i += 8)
        tile[ty + i][tx] = in[(size_t)(r0 + ty + i) * Cc + c0 + tx];
    __syncthreads();
#pragma unroll
    for (int i = 0; i < 32; i += 8)
        out[(size_t)(c0 + ty + i) * R + r0 + tx] = f2bf(tile[tx][ty + i]);
}

// ---------------------------------------------------------------------------
// 256x256-tile 8-wave 8-phase MFMA GEMM (faithful m201-template port).
// BK=64, 2 K-tiles per iteration (kt even -> lds[0], odd -> lds[1]).
// Waves 2M x 4N: wave (wr,wc) owns rows wr*128+[0,128), cols wc*64+[0,64);
// each wave touches ONE A-half and ONE B-half only.
// Per K-tile, 4 phases x 16 MFMA (C-quadrants), B frags held in regs:
//   ph0: read B n0-1 (4) + A m0-3 (8)          -> MFMA m0-3 x n0-1
//   ph1: read B n2-3 (4)                        -> MFMA m0-3 x n2-3
//   ph2: read A m4-7 (8); stage next B  -> cb   -> MFMA m4-7 x n2-3
//   ph3: stage next A -> cb                     -> MFMA m4-7 x n0-1
// Region safety: cb.B fully read by end ph1 (B held in regs afterward),
// staged at ph2 (issued after ph1's closing barrier); cb.A fully read by
// end ph2 (drained at ph2's lgkmcnt(0)), staged at ph3. Each phase:
// [reads; stages] BARRIER lgkmcnt(0)+sched_barrier MFMA BARRIER.
// vmcnt ledger (8 issues per K-tile per wave, FIFO):
//   steady state 8 outstanding at iteration start (next odd tile);
//   vmcnt(8) at end of ph3 (drains b1's data before ph4 reads it) and at
//   end of ph7 (drains kt+2 before next iter's ph0). Tail: vmcnt(0) at
//   ph3-end of the last iteration; no stages there.
// Swizzle (rule 21): linear gload_lds dest + inverse-XOR'd global source
// (slot ^= row&7) + same XOR on ds_read -> 0 bank conflicts (proven r1/r2).
// ---------------------------------------------------------------------------
template <int OUT_BF16>
__global__ __launch_bounds__(512, 2) void gemm_bf16_8ph(
    const u16* __restrict__ A,    // [M][K] bf16
    const u16* __restrict__ Bt,   // [N][K] bf16 (B transposed)
    const float* __restrict__ bias,
    void* __restrict__ Cout,      // bf16 [M][N] or fp32 [M][N]
    int M, int N, int K, int gx)  // gx = N/256
{
    __shared__ alignas(16) char lds[2][65536];  // [buf][A 32K | B 32K]

    const int tid  = threadIdx.x;
    const int lane = tid & 63;
    const int w    = tid >> 6;      // 0..7
    const int wr   = w >> 2;        // 0..1 (M)
    const int wc   = w & 3;         // 0..3 (N)
    const int l15  = lane & 15;
    const int l4   = lane >> 4;

    // XCD-aware swizzle (bijective: gridDim.x % 8 == 0)
    const int nwg = gridDim.x;
    const int cpx = nwg >> 3;
    const int swz = (blockIdx.x & 7) * cpx + (blockIdx.x >> 3);
    const int bx  = swz % gx, by = swz / gx;
    const int m0  = by * 256;
    const int n0  = bx * 256;
    const int NT  = K >> 6;         // K-tiles of 64
    const int NI  = NT >> 1;        // iterations (2 K-tiles each)

    f32x4 acc[8][4] = {};

    // staging geometry: per half-tile (128 rows x 128B) each wave issues 2
    // gload_lds(16B); HW writes dest + lane*16. row = w*16 + i*8 + (lane>>3);
    // physical slot = lane&7; source slot pre-XOR'd with row&7.
    const int srow  = w * 16 + (lane >> 3);
    const int sslot = (lane & 7) ^ (lane >> 3);
    const size_t abase = (size_t)(m0 + srow) * K + sslot * 8;
    const size_t bbase = (size_t)(n0 + srow) * K + sslot * 8;
    const int sdst = w * 2048;

    // stage one 128-row half-tile: mat 0=A,1=B; hh = half
    auto stage = [&](char* buf, int mat, int hh, int k0) {
        const u16* srcp = mat ? Bt : A;
        const size_t base = mat ? bbase : abase;
#pragma unroll
        for (int i = 0; i < 2; ++i)
            __builtin_amdgcn_global_load_lds(
                AS1C(srcp + base + (size_t)(hh * 128 + i * 8) * K + k0),
                AS3(buf + mat * 32768 + hh * 16384 + sdst + i * 1024), 16, 0, 0);
    };

    const int sl0 = (l4 ^ (l15 & 7)) << 4;

    auto rdA = [&](char* cb, bf16x8 (&afr)[4][2], int mbase) {
#pragma unroll
        for (int mt = 0; mt < 4; ++mt) {
            const int rb = (wr * 128 + (mbase + mt) * 16 + l15) * 128;
            afr[mt][0] = __builtin_bit_cast(bf16x8, *(const uint4*)(cb + rb + sl0));
            afr[mt][1] = __builtin_bit_cast(bf16x8, *(const uint4*)(cb + rb + (sl0 ^ 64)));
        }
    };
    auto rdB = [&](char* cb, bf16x8 (&bfr)[4][2], int nbase) {
#pragma unroll
        for (int nt = 0; nt < 2; ++nt) {
            const int rb = 32768 + (wc * 64 + (nbase + nt) * 16 + l15) * 128;
            bfr[nbase + nt][0] = __builtin_bit_cast(bf16x8, *(const uint4*)(cb + rb + sl0));
            bfr[nbase + nt][1] = __builtin_bit_cast(bf16x8, *(const uint4*)(cb + rb + (sl0 ^ 64)));
        }
    };
    auto quad = [&](bf16x8 (&afr)[4][2], bf16x8 (&bfr)[4][2], int mb, int nb) {
        __builtin_amdgcn_s_setprio(1);
#pragma unroll
        for (int mt = 0; mt < 4; ++mt)
#pragma unroll
            for (int nt = 0; nt < 2; ++nt)
#pragma unroll
                for (int kk = 0; kk < 2; ++kk)
                    acc[mb + mt][nb + nt] = __builtin_amdgcn_mfma_f32_16x16x32_bf16(
                        afr[mt][kk], bfr[nb + nt][kk], acc[mb + mt][nb + nt], 0, 0, 0);
        __builtin_amdgcn_s_setprio(0);
    };

    // prologue: kt0 (B,A halves) -> lds[0]; kt1 -> lds[1]. 16 issues.
    stage(lds[0], 1, 0, 0);  stage(lds[0], 1, 1, 0);
    stage(lds[0], 0, 0, 0);  stage(lds[0], 0, 1, 0);
    stage(lds[1], 1, 0, 64); stage(lds[1], 1, 1, 64);
    stage(lds[1], 0, 0, 64); stage(lds[1], 0, 1, 64);
    asm volatile("s_waitcnt vmcnt(8)" ::: "memory");   // kt0 resident
    ph_barrier();

    for (int it = 0; it < NI; ++it) {
        const bool st = (it + 1 < NI);
#pragma unroll
        for (int hf = 0; hf < 2; ++hf) {
            char* cb = lds[hf];
            const int kS = (2 * it + 2 + hf) << 6;     // staged K-tile offset
            bf16x8 afr[4][2], bfr[4][2];

            // ---- ph0/ph4: B n0-1 + A m0-3 ------------------------------
            rdB(cb, bfr, 0);
            rdA(cb, afr, 0);
            ph_barrier(); lgkm0();
            quad(afr, bfr, 0, 0);
            ph_barrier();

            // ---- ph1/ph5: B n2-3 ---------------------------------------
            rdB(cb, bfr, 2);
            ph_barrier(); lgkm0();
            quad(afr, bfr, 0, 2);
            ph_barrier();

            // ---- ph2/ph6: A m4-7; stage next B -> cb -------------------
            rdA(cb, afr, 4);
            if (st) { stage(cb, 1, 0, kS); stage(cb, 1, 1, kS); }
            ph_barrier(); lgkm0();
            quad(afr, bfr, 4, 2);
            ph_barrier();

            // ---- ph3/ph7: stage next A -> cb; MFMA m4-7 x n0-1 ---------
            if (st) { stage(cb, 0, 0, kS); stage(cb, 0, 1, kS); }
            ph_barrier();
            quad(afr, bfr, 4, 0);
            if (st)
                asm volatile("s_waitcnt vmcnt(8)" ::: "memory");
            else if (hf == 0)
                asm volatile("s_waitcnt vmcnt(0)" ::: "memory");
            ph_barrier();
        }
    }

    // epilogue: C/D layout row=l4*4+reg, col=l15
#pragma unroll
    for (int nt = 0; nt < 4; ++nt) {
        const int colg = n0 + wc * 64 + nt * 16 + l15;
        const float bv = bias[colg];
#pragma unroll
        for (int mt = 0; mt < 8; ++mt) {
            const int rowb = m0 + wr * 128 + mt * 16 + l4 * 4;
#pragma unroll
            for (int r = 0; r < 4; ++r) {
                const float v = acc[mt][nt][r] + bv;
                if (OUT_BF16)
                    ((u16*)Cout)[(size_t)(rowb + r) * N + colg] = f2bf(v);
                else
                    ((float*)Cout)[(size_t)(rowb + r) * N + colg] = v;
            }
        }
    }
}

// ---------------------------------------------------------------------------
// 256x128-tile 8-wave pipelined MFMA GEMM (round-1 proven form, kept for the
// proj GEMM where grid 16x16 = 256 blocks = exactly 1 round).
// ---------------------------------------------------------------------------
template <int OUT_BF16>
__global__ __launch_bounds__(512, 2) void gemm_bf16_256(
    const u16* __restrict__ A,    // [M][K] bf16
    const u16* __restrict__ Bt,   // [N][K] bf16 (B transposed)
    const float* __restrict__ bias,
    void* __restrict__ Cout,      // bf16 [M][N] or fp32 [M][N]
    int M, int N, int K)
{
    __shared__ alignas(16) char lds[2][49152];   // [buf][A 32KB | B 16KB]

    const int tid  = threadIdx.x;
    const int lane = tid & 63;
    const int w    = tid >> 6;      // 0..7
    const int wr   = w >> 1;        // 0..3 (M)
    const int wc   = w & 1;         // 0..1 (N)
    const int l15  = lane & 15;
    const int l4   = lane >> 4;
    const int m0   = blockIdx.y * 256;
    const int n0   = blockIdx.x * 128;
    const int NT   = K >> 6;        // K-tiles of 64

    f32x4 acc[4][4] = {};

    const int srow  = w * 16 + (lane >> 3);          // +i*8 per issue
    const int sslot = (lane & 7) ^ (lane >> 3);      // row&7 == lane>>3
    const size_t aoff = (size_t)(m0 + srow) * K + sslot * 8;
    const size_t boff = (size_t)(n0 + srow) * K + sslot * 8;
    const int sdst = w * 2048;

    auto stageA = [&](char* buf, int h, int k0) {
#pragma unroll
        for (int i = 0; i < 2; ++i)
            __builtin_amdgcn_global_load_lds(
                AS1C(A + aoff + (size_t)(h * 128 + i * 8) * K + k0),
                AS3(buf + h * 16384 + sdst + i * 1024), 16, 0, 0);
    };
    auto stageB = [&](char* buf, int k0) {
#pragma unroll
        for (int i = 0; i < 2; ++i)
            __builtin_amdgcn_global_load_lds(
                AS1C(Bt + boff + (size_t)(i * 8) * K + k0),
                AS3(buf + 32768 + sdst + i * 1024), 16, 0, 0);
    };

    stageB(lds[0], 0);
    stageA(lds[0], 0, 0);
    stageA(lds[0], 1, 0);
    stageB(lds[1], 64);
    stageA(lds[1], 0, 64);
    asm volatile("s_waitcnt vmcnt(4)" ::: "memory");
    __builtin_amdgcn_s_barrier();

    const int sl0  = (l4 ^ (l15 & 7)) << 4;
    const int sl1  = sl0 ^ 64;
    const int arow = (wr * 32 + l15) * 128;            // within an A-half
    const int brow = 32768 + (wc * 64 + l15) * 128;

    for (int kt = 0; kt < NT; ++kt) {
        char* cb = lds[kt & 1];
        char* nb = lds[(kt & 1) ^ 1];

        // ---------------- phase 1: B(all) + A(h0), MFMA m-reps 0-1 --------
        bf16x8 bfr[4][2], af[2][2];
#pragma unroll
        for (int nt = 0; nt < 4; ++nt) {
            bfr[nt][0] = __builtin_bit_cast(bf16x8,
                *(const uint4*)(cb + brow + nt * 2048 + sl0));
            bfr[nt][1] = __builtin_bit_cast(bf16x8,
                *(const uint4*)(cb + brow + nt * 2048 + sl1));
        }
#pragma unroll
        for (int mt = 0; mt < 2; ++mt) {
            af[mt][0] = __builtin_bit_cast(bf16x8,
                *(const uint4*)(cb + arow + mt * 2048 + sl0));
            af[mt][1] = __builtin_bit_cast(bf16x8,
                *(const uint4*)(cb + arow + mt * 2048 + sl1));
        }
        if (kt + 1 < NT) stageA(nb, 1, (kt + 1) << 6);   // (kt+1):Ah1
        __builtin_amdgcn_s_barrier();
        asm volatile("s_waitcnt lgkmcnt(0)" ::: "memory");
        __builtin_amdgcn_s_setprio(1);
#pragma unroll
        for (int mt = 0; mt < 2; ++mt)
#pragma unroll
            for (int nt = 0; nt < 4; ++nt)
#pragma unroll
                for (int kk = 0; kk < 2; ++kk)
                    acc[mt][nt] = __builtin_amdgcn_mfma_f32_16x16x32_bf16(
                        af[mt][kk], bfr[nt][kk], acc[mt][nt], 0, 0, 0);
        __builtin_amdgcn_s_setprio(0);
        __builtin_amdgcn_s_barrier();

        // ---------------- phase 2: A(h1), MFMA m-reps 2-3 -----------------
        bf16x8 ag[2][2];
#pragma unroll
        for (int mt = 0; mt < 2; ++mt) {
            ag[mt][0] = __builtin_bit_cast(bf16x8,
                *(const uint4*)(cb + 16384 + arow + mt * 2048 + sl0));
            ag[mt][1] = __builtin_bit_cast(bf16x8,
                *(const uint4*)(cb + 16384 + arow + mt * 2048 + sl1));
        }
        if (kt + 2 < NT) {                               // (kt+2):{B,Ah0}
            stageB(cb, (kt + 2) << 6);
            stageA(cb, 0, (kt + 2) << 6);
        }
        __builtin_amdgcn_s_barrier();
        asm volatile("s_waitcnt lgkmcnt(0)" ::: "memory");
        __builtin_amdgcn_s_setprio(1);
#pragma unroll
        for (int mt = 0; mt < 2; ++mt)
#pragma unroll
            for (int nt = 0; nt < 4; ++nt)
#pragma unroll
                for (int kk = 0; kk < 2; ++kk)
                    acc[mt + 2][nt] = __builtin_amdgcn_mfma_f32_16x16x32_bf16(
                        ag[mt][kk], bfr[nt][kk], acc[mt + 2][nt], 0, 0, 0);
        __builtin_amdgcn_s_setprio(0);
        if (kt < NT - 2)
            asm volatile("s_waitcnt vmcnt(4)" ::: "memory");
        else
            asm volatile("s_waitcnt vmcnt(0)" ::: "memory");
        __builtin_amdgcn_s_barrier();
    }

    // epilogue: C/D layout row=l4*4+reg, col=l15
#pragma unroll
    for (int nt = 0; nt < 4; ++nt) {
        const int colg = n0 + wc * 64 + nt * 16 + l15;
        const float bv = bias[colg];
#pragma unroll
        for (int mt = 0; mt < 4; ++mt) {
            const int rowb = m0 + (mt < 2 ? wr * 32 + mt * 16
                                          : 128 + wr * 32 + (mt - 2) * 16) + l4 * 4;
#pragma unroll
            for (int r = 0; r < 4; ++r) {
                const float v = acc[mt][nt][r] + bv;
                if (OUT_BF16)
                    ((u16*)Cout)[(size_t)(rowb + r) * N + colg] = f2bf(v);
                else
                    ((float*)Cout)[(size_t)(rowb + r) * N + colg] = v;
            }
        }
    }
}

// ---------------------------------------------------------------------------
// RoPE cos/sin table: ct/st[t][d2], d2 in [0,64).
// ---------------------------------------------------------------------------
__global__ __launch_bounds__(256) void rope_table(
    float* __restrict__ ct, float* __restrict__ st)
{
    const int i = blockIdx.x * 256 + threadIdx.x;   // t*64 + d2
    const int d2 = i & 63, t = i >> 6;
    const float invf = expf(-(float)d2 * (9.210340371976184f / 64.0f));
    const float fr = (float)t * invf;
    ct[i] = cosf(fr);
    st[i] = sinf(fr);
}

// ---------------------------------------------------------------------------
// Fused RoPE + QKV relayout (single pass over qkv):
//   Qc[bh][t][d] = rope(q),  Kc[bh][t][d] = rope(k),  Vt[bh][d][t] = v.
// V path now LDS-staged: per-thread column write into vtile, then fully
// coalesced uint4 row-segment stores (old version: 128 scalar u16 global
// stores per thread at 2KB stride).
// ---------------------------------------------------------------------------
__global__ __launch_bounds__(256) void rope_kv(
    const u16* __restrict__ qkv, const float* __restrict__ ct,
    const float* __restrict__ st,
    u16* __restrict__ Qc, u16* __restrict__ Kc, u16* __restrict__ Vt)
{
    __shared__ u16 vtile[128][264];      // 264 = 256 + 8 pad (16B-aligned rows)
    const int tid = threadIdx.x;
    const int blk = blockIdx.x;          // b(4) x h(16) x ttile(4)
    const int tt = blk & 3;
    const int h  = (blk >> 2) & 15;
    const int b  = blk >> 6;
    const int t  = tt * 256 + tid;
    const int bh = b * 16 + h;

    const size_t src  = ((size_t)(b * T_SEQ + t)) * QKV_N + h * D_HEAD;
    const size_t dst  = ((size_t)(bh * T_SEQ + t)) * D_HEAD;
    const float* crow = ct + t * 64;
    const float* srow = st + t * 64;

#pragma unroll
    for (int part = 0; part < 2; ++part) {
        const u16* in  = qkv + src + part * C_DIM;
        u16* outp      = (part ? Kc : Qc) + dst;
#pragma unroll
        for (int c = 0; c < 8; ++c) {
            uint4 u1 = *(const uint4*)(in + c * 8);
            uint4 u2 = *(const uint4*)(in + 64 + c * 8);
            float f1[8], f2[8], o1[8], o2[8];
            unpack8(u1, f1); unpack8(u2, f2);
#pragma unroll
            for (int i = 0; i < 8; ++i) {
                const float cv = crow[c * 8 + i], sv = srow[c * 8 + i];
                o1[i] = f1[i] * cv - f2[i] * sv;
                o2[i] = f1[i] * sv + f2[i] * cv;
            }
            *(uint4*)(outp + c * 8)      = pack8(o1);
            *(uint4*)(outp + 64 + c * 8) = pack8(o2);
        }
    }

    // V -> LDS (thread owns column t_local = tid)
#pragma unroll
    for (int c = 0; c < 16; ++c) {
        uint4 v = *(const uint4*)(qkv + src + 2 * C_DIM + c * 8);
        u16 e[8];
        e[0] = (u16)(v.x & 0xffff); e[1] = (u16)(v.x >> 16);
        e[2] = (u16)(v.y & 0xffff); e[3] = (u16)(v.y >> 16);
        e[4] = (u16)(v.z & 0xffff); e[5] = (u16)(v.z >> 16);
        e[6] = (u16)(v.w & 0xffff); e[7] = (u16)(v.w >> 16);
#pragma unroll
        for (int j = 0; j < 8; ++j)
            vtile[c * 8 + j][tid] = e[j];
    }
    __syncthreads();

    // coalesced store: 32 lanes cover one row's 256 u16 (512B contiguous)
    const int dl = tid >> 5;             // 0..7: row within pass
    const int jc = (tid & 31) * 8;       // u16 col
    u16* vt = Vt + ((size_t)bh * D_HEAD) * T_SEQ + (size_t)tt * 256;
#pragma unroll
    for (int pass = 0; pass < 16; ++pass) {
        const int d = pass * 8 + dl;
        *(uint4*)(vt + (size_t)d * T_SEQ + jc) = *(const uint4*)&vtile[d][jc];
    }
}

// ---------------------------------------------------------------------------
// MFMA flash attention, 64-row q-tiles (R6 geometry: 3->2 blocks/CU) with
// DOUBLE-BUFFERED K/V staging: loads for k-tile kt+1 issued right after the
// barrier, in flight across kt's QK/softmax/PV compute. Load-balanced pairing
// (qt = p and 15-p). Fixed-shift softmax P=exp(s-8) (scores ~N(0,1)), single
// end normalization.
// ---------------------------------------------------------------------------
__global__ __launch_bounds__(256) void attn_mfma(
    const u16* __restrict__ Qc,    // [B*H, T, D] roped
    const u16* __restrict__ Kc,    // [B*H, T, D] roped
    const u16* __restrict__ Vt,    // [B*H, D, T]
    u16* __restrict__ y)           // [B, T, C]
{
    __shared__ alignas(16) char KsL[2][16384];   // [cd(16)][row(64)][16B]
    __shared__ alignas(16) char VtsL[2][16384];  // [jc(8)][drow(128)][16B]
    __shared__ alignas(16) char PwL[4][2176];    // per-wave [jc(8)][q(16)][16B]+pad

    const int tid  = threadIdx.x;
    const int lane = tid & 63;
    const int w    = tid >> 6;
    const int l15  = lane & 15;
    const int l4   = lane >> 4;
    const int p    = blockIdx.x;     // 0..7
    const int bh   = blockIdx.y;     // 0..63
    const int h    = bh & 15;
    const int b    = bh >> 4;

    const size_t kbase = (size_t)bh * T_SEQ * D_HEAD;
    const size_t vbase = (size_t)bh * D_HEAD * T_SEQ;
    const float scale = 0.08838834764831845f;   // 1/sqrt(128)
    char* pw = PwL[w];

    for (int half = 0; half < 2; ++half) {
        const int qt = half ? (15 - p) : p;

        // Q fragments (A-layout: m=lane&15, k=(lane>>4)*8+j)
        const int qrow = qt * 64 + w * 16 + l15;
        const u16* qptr = Qc + ((size_t)(bh * T_SEQ + qrow)) * D_HEAD;
        bf16x8 qf[4];
#pragma unroll
        for (int f = 0; f < 4; ++f)
            qf[f] = __builtin_bit_cast(bf16x8, *(const uint4*)(qptr + f * 32 + l4 * 8));

        f32x4 o[8] = {};                 // O[q=l4*4+r][d=db*16+l15]
        float lrow[4] = {};              // per-lane partial denominators

        __syncthreads();   // prior half's readers done before restaging buf 0

        // prologue: stage kt = 0 into buffer 0
        {
            const u16* ksrc = Kc + kbase + (size_t)(0 * 64 + lane) * D_HEAD;
#pragma unroll
            for (int i = 0; i < 4; ++i) {
                const int cd = w * 4 + i;
                __builtin_amdgcn_global_load_lds(AS1C(ksrc + cd * 8),
                                                 AS3(KsL[0] + cd * 1024), 16, 0, 0);
            }
#pragma unroll
            for (int i = 0; i < 4; ++i) {
                const int jc = w + (i >> 1) * 4;
                const int dh = i & 1;
                const u16* vsrc = Vt + vbase + (size_t)(dh * 64 + lane) * T_SEQ
                                  + 0 * 64 + jc * 8;
                __builtin_amdgcn_global_load_lds(AS1C(vsrc),
                                                 AS3(VtsL[0] + jc * 2048 + dh * 1024), 16, 0, 0);
            }
        }

        int buf = 0;
        for (int kt = 0; kt <= qt; ++kt, buf ^= 1) {
            __syncthreads();     // buf visible; buf^1's readers (kt-2) done
            if (kt < qt) {
                const int kn = kt + 1;
                char* kb = KsL[buf ^ 1];
                char* vb = VtsL[buf ^ 1];
                const u16* ksrc = Kc + kbase + (size_t)(kn * 64 + lane) * D_HEAD;
#pragma unroll
                for (int i = 0; i < 4; ++i) {
                    const int cd = w * 4 + i;
                    __builtin_amdgcn_global_load_lds(AS1C(ksrc + cd * 8),
                                                     AS3(kb + cd * 1024), 16, 0, 0);
                }
#pragma unroll
                for (int i = 0; i < 4; ++i) {
                    const int jc = w + (i >> 1) * 4;
                    const int dh = i & 1;
                    const u16* vsrc = Vt + vbase + (size_t)(dh * 64 + lane) * T_SEQ
                                      + kn * 64 + jc * 8;
                    __builtin_amdgcn_global_load_lds(AS1C(vsrc),
                                                     AS3(vb + jc * 2048 + dh * 1024), 16, 0, 0);
                }
            }

            const char* kbuf = KsL[buf];
            const char* vbuf = VtsL[buf];

            // QK^T: 16 MFMAs
            f32x4 sacc[4] = {};
#pragma unroll
            for (int nb = 0; nb < 4; ++nb)
#pragma unroll
                for (int kc = 0; kc < 4; ++kc) {
                    bf16x8 kf = __builtin_bit_cast(bf16x8,
                        *(const uint4*)(kbuf + (kc * 4 + l4) * 1024 + (nb * 16 + l15) * 16));
                    sacc[nb] = __builtin_amdgcn_mfma_f32_16x16x32_bf16(
                        qf[kc], kf, sacc[nb], 0, 0, 0);
                }

            // P = exp(s*scale - 8), causal-masked on diagonal; partial denoms
#pragma unroll
            for (int nb = 0; nb < 4; ++nb)
#pragma unroll
                for (int r = 0; r < 4; ++r) {
                    const bool masked =
                        (kt == qt) && ((nb * 16 + l15) > (w * 16 + l4 * 4 + r));
                    const float e = masked ? 0.f
                        : __expf(sacc[nb][r] * scale - 8.0f);
                    sacc[nb][r] = e;
                    lrow[r] += e;
                }

            // P: C-layout regs -> bf16 -> per-wave LDS in A-layout chunks
#pragma unroll
            for (int nb = 0; nb < 4; ++nb)
#pragma unroll
                for (int r = 0; r < 4; ++r) {
                    const int j = nb * 16 + l15;
                    const int q = l4 * 4 + r;
                    *(u16*)(pw + (j >> 3) * 272 + q * 16 + (j & 7) * 2) =
                        f2bf(sacc[nb][r]);
                }

            // PV: O += P @ V
            bf16x8 pf[2];
#pragma unroll
            for (int kc2 = 0; kc2 < 2; ++kc2)
                pf[kc2] = __builtin_bit_cast(bf16x8,
                    *(const uint4*)(pw + (kc2 * 4 + l4) * 272 + l15 * 16));
#pragma unroll
            for (int db = 0; db < 8; ++db)
#pragma unroll
                for (int kc2 = 0; kc2 < 2; ++kc2) {
                    bf16x8 vf = __builtin_bit_cast(bf16x8,
                        *(const uint4*)(vbuf + (kc2 * 4 + l4) * 2048 + (db * 16 + l15) * 16));
                    o[db] = __builtin_amdgcn_mfma_f32_16x16x32_bf16(
                        pf[kc2], vf, o[db], 0, 0, 0);
                }
        }

        // end-of-row reduce of denominators across the 16 l15 lanes
        float inv[4];
#pragma unroll
        for (int r = 0; r < 4; ++r) {
            float ls = lrow[r];
#pragma unroll
            for (int off = 1; off < 16; off <<= 1)
                ls += __shfl_xor(ls, off, 64);
            inv[r] = 1.f / ls;
        }
#pragma unroll
        for (int db = 0; db < 8; ++db)
#pragma unroll
            for (int r = 0; r < 4; ++r) {
                const int q = qt * 64 + w * 16 + l4 * 4 + r;
                const int d = h * D_HEAD + db * 16 + l15;
                y[(size_t)(b * T_SEQ + q) * C_DIM + d] = f2bf(o[db][r] * inv[r]);
            }
    }
}

// ---------------------------------------------------------------------------
extern "C" void kernel_launch(void* const* d_in, const int* in_sizes, int n_in,
                              void* d_out, int out_size, void* d_ws, size_t ws_size,
                              hipStream_t stream) {
    const float* x      = (const float*)d_in[0];
    const float* w_attn = (const float*)d_in[1];
    const float* b_attn = (const float*)d_in[2];
    const float* w_proj = (const float*)d_in[3];
    const float* b_proj = (const float*)d_in[4];
    float* out = (float*)d_out;

    char* ws = (char*)d_ws;
    u16* xb   = (u16*)(ws);                        // [4096][2048]    16.78 MB
    u16* waT  = (u16*)(ws + 16777216);             // [6144][2048]    25.17 MB
    u16* Qc   = (u16*)(ws);                        // [64][1024][128] 16.78 MB
    u16* Kc   = (u16*)(ws + 16777216);             // [64][1024][128] 16.78 MB
    u16* Vt   = (u16*)(ws + 33554432);             // [64][128][1024] 16.78 MB
    u16* qkvb = (u16*)(ws + 50331648);             // [4096][6144]    50.33 MB
    u16* wpT  = (u16*)(ws + 50331648);             // [2048][2048]     8.39 MB (after rope_kv)
    u16* yb   = (u16*)(ws + 100663296);            // [4096][2048]    16.78 MB
    float* ct = (float*)(ws + 100663296);          // [1024][64] 256 KB (dead before attn)
    float* st = ct + 65536;

    cast_bf16<<<(BT * C_DIM / 4) / 256, 256, 0, stream>>>(x, xb);
    transpose_cast<<<dim3(QKV_N / 32, C_DIM / 32), 256, 0, stream>>>(w_attn, waT, C_DIM, QKV_N);
    rope_table<<<(T_SEQ * 64) / 256, 256, 0, stream>>>(ct, st);

    gemm_bf16_8ph<1><<<dim3((QKV_N / 256) * (BT / 256)), 512, 0, stream>>>(
        xb, waT, b_attn, qkvb, BT, QKV_N, C_DIM, QKV_N / 256);

    rope_kv<<<256, 256, 0, stream>>>(qkvb, ct, st, Qc, Kc, Vt);

    transpose_cast<<<dim3(C_DIM / 32, C_DIM / 32), 256, 0, stream>>>(w_proj, wpT, C_DIM, C_DIM);

    attn_mfma<<<dim3(8, 4 * H_NUM), 256, 0, stream>>>(Qc, Kc, Vt, yb);

    gemm_bf16_256<0><<<dim3(C_DIM / 128, BT / 256), 512, 0, stream>>>(
        yb, wpT, b_proj, out, BT, C_DIM, C_DIM);
}

// Round 4
// 394.538 us; speedup vs baseline: 1.0520x; 1.0520x over previous
//
#include <hip/hip_runtime.h>
#include <math.h>

#define T_SEQ 1024
#define C_DIM 2048
#define H_NUM 16
#define D_HEAD 128
#define BT 4096              // B*T rows
#define QKV_N 6144           // 3*C

typedef __bf16 bf16x8 __attribute__((ext_vector_type(8)));
typedef float f32x4 __attribute__((ext_vector_type(4)));
typedef unsigned short u16;
typedef unsigned int u32;

#define AS1C(p) ((const __attribute__((address_space(1))) void*)(p))
#define AS3(p)  ((__attribute__((address_space(3))) void*)(p))

__device__ __forceinline__ u16 f2bf(float f) {
    u32 u = __builtin_bit_cast(u32, f);
    u += 0x7fffu + ((u >> 16) & 1u);          // RNE
    return (u16)(u >> 16);
}
__device__ __forceinline__ void unpack8(uint4 u, float* f) {
    const u32 w0 = u.x, w1 = u.y, w2 = u.z, w3 = u.w;
    f[0] = __builtin_bit_cast(float, w0 << 16);
    f[1] = __builtin_bit_cast(float, w0 & 0xffff0000u);
    f[2] = __builtin_bit_cast(float, w1 << 16);
    f[3] = __builtin_bit_cast(float, w1 & 0xffff0000u);
    f[4] = __builtin_bit_cast(float, w2 << 16);
    f[5] = __builtin_bit_cast(float, w2 & 0xffff0000u);
    f[6] = __builtin_bit_cast(float, w3 << 16);
    f[7] = __builtin_bit_cast(float, w3 & 0xffff0000u);
}
__device__ __forceinline__ uint4 pack8(const float* f) {
    uint4 u;
    u.x = (u32)f2bf(f[0]) | ((u32)f2bf(f[1]) << 16);
    u.y = (u32)f2bf(f[2]) | ((u32)f2bf(f[3]) << 16);
    u.z = (u32)f2bf(f[4]) | ((u32)f2bf(f[5]) << 16);
    u.w = (u32)f2bf(f[6]) | ((u32)f2bf(f[7]) << 16);
    return u;
}

__device__ __forceinline__ void ph_barrier() {
    asm volatile("" ::: "memory");
    __builtin_amdgcn_s_barrier();
    asm volatile("" ::: "memory");
}

// ---------------------------------------------------------------------------
// Elementwise fp32 -> bf16 cast (x -> xb).
// ---------------------------------------------------------------------------
__global__ __launch_bounds__(256) void cast_bf16(
    const float* __restrict__ in, u16* __restrict__ out)
{
    int i = blockIdx.x * 256 + threadIdx.x;
    float4 v = ((const float4*)in)[i];
    ushort4 o;
    o.x = f2bf(v.x); o.y = f2bf(v.y); o.z = f2bf(v.z); o.w = f2bf(v.w);
    ((ushort4*)out)[i] = o;
}

// ---------------------------------------------------------------------------
// fp32 [R][Cc] -> bf16 [Cc][R] transpose+cast. 32x32 tile, 256 threads.
// ---------------------------------------------------------------------------
__global__ __launch_bounds__(256) void transpose_cast(
    const float* __restrict__ in, u16* __restrict__ out, int R, int Cc)
{
    __shared__ float tile[32][33];
    const int c0 = blockIdx.x * 32, r0 = blockIdx.y * 32;
    const int tx = threadIdx.x & 31, ty = threadIdx.x >> 5;  // ty 0..7
#pragma unroll
    for (int i = 0; i < 32; i += 8)
        tile[ty + i][tx] = in[(size_t)(r0 + ty + i) * Cc + c0 + tx];
    __syncthreads();
#pragma unroll
    for (int i = 0; i < 32; i += 8)
        out[(size_t)(c0 + ty + i) * R + r0 + tx] = f2bf(tile[tx][ty + i]);
}

// ---------------------------------------------------------------------------
// 256x256-tile 8-wave 4-phase MFMA GEMM.  Round-4 revision of the 8-phase
// port, fixing the two regressions the r3 counters isolated:
//   (1) NO XCD swizzle (r3: FETCH_SIZE 90->176 MB — the remap scattered
//       locality under the actual dispatch order). Plain 2D grid.
//   (2) NO forced lgkmcnt(0)/sched_barrier and NO mid-phase barrier (r3:
//       5313 cy/K-tile == serial LDS+MFMA sum; the fences created lockstep).
//       Reads are plain C++ ds_reads: the compiler emits counted lgkmcnt per
//       dependency, so each wave's LDS drain overlaps MFMA issue.
// Geometry: BK=64, 2 K-tiles/iter (kt even->lds[0], odd->lds[1]). Waves
// 2M x 4N, per-wave 128x64; B frags (8 regs-pairs) held across phases.
// Per K-tile, 4 phases, each ending in ONE barrier:
//   ph0: read B n0-1 (4) + A m0-3 (8)   -> MFMA m0-3 x n0-1 | bar
//   ph1: read B n2-3 (4)                -> MFMA m0-3 x n2-3 | bar
//   ph2: read A m4-7 (8); stage next B  -> MFMA m4-7 x n2-3 | bar
//   ph3: stage next A                   -> MFMA m4-7 x n0-1 | vmcnt | bar
// Safety: every ds_read has an in-phase MFMA consumer, so a wave reaching a
// trailing barrier has drained all its reads of the buffer regions that the
// NEXT phase stages into (cb.B fully read by end ph1, staged ph2; cb.A fully
// read by end ph2, staged ph3).  gload_lds visibility is via the vmcnt
// ledger: 8 issues/K-tile; vmcnt(8) at ph3-end leaves only kt+2's loads in
// flight => kt+1 resident before its reads. vmcnt(0) only in the tail.
// Swizzle (rule 21): linear gload_lds dest + inverse-XOR'd global source
// (slot ^= row&7) + same XOR on ds_read -> 0 bank conflicts (proven r1-r3).
// ---------------------------------------------------------------------------
template <int OUT_BF16>
__global__ __launch_bounds__(512, 2) void gemm_bf16_8ph(
    const u16* __restrict__ A,    // [M][K] bf16
    const u16* __restrict__ Bt,   // [N][K] bf16 (B transposed)
    const float* __restrict__ bias,
    void* __restrict__ Cout,      // bf16 [M][N] or fp32 [M][N]
    int M, int N, int K)
{
    __shared__ alignas(16) char lds[2][65536];  // [buf][A 32K | B 32K]

    const int tid  = threadIdx.x;
    const int lane = tid & 63;
    const int w    = tid >> 6;      // 0..7
    const int wr   = w >> 2;        // 0..1 (M)
    const int wc   = w & 3;         // 0..3 (N)
    const int l15  = lane & 15;
    const int l4   = lane >> 4;
    const int m0   = blockIdx.y * 256;
    const int n0   = blockIdx.x * 256;
    const int NT   = K >> 6;        // K-tiles of 64
    const int NI   = NT >> 1;       // iterations (2 K-tiles each)

    f32x4 acc[8][4] = {};

    // staging geometry: per half-tile (128 rows x 128B) each wave issues 2
    // gload_lds(16B); HW writes dest + lane*16. row = w*16 + i*8 + (lane>>3);
    // physical slot = lane&7; source slot pre-XOR'd with row&7.
    const int srow  = w * 16 + (lane >> 3);
    const int sslot = (lane & 7) ^ (lane >> 3);
    const size_t abase = (size_t)(m0 + srow) * K + sslot * 8;
    const size_t bbase = (size_t)(n0 + srow) * K + sslot * 8;
    const int sdst = w * 2048;

    // stage one 128-row half-tile: mat 0=A,1=B; hh = half
    auto stage = [&](char* buf, int mat, int hh, int k0) {
        const u16* srcp = mat ? Bt : A;
        const size_t base = mat ? bbase : abase;
#pragma unroll
        for (int i = 0; i < 2; ++i)
            __builtin_amdgcn_global_load_lds(
                AS1C(srcp + base + (size_t)(hh * 128 + i * 8) * K + k0),
                AS3(buf + mat * 32768 + hh * 16384 + sdst + i * 1024), 16, 0, 0);
    };

    const int sl0 = (l4 ^ (l15 & 7)) << 4;

    auto rdA = [&](char* cb, bf16x8 (&afr)[4][2], int mbase) {
#pragma unroll
        for (int mt = 0; mt < 4; ++mt) {
            const int rb = (wr * 128 + (mbase + mt) * 16 + l15) * 128;
            afr[mt][0] = __builtin_bit_cast(bf16x8, *(const uint4*)(cb + rb + sl0));
            afr[mt][1] = __builtin_bit_cast(bf16x8, *(const uint4*)(cb + rb + (sl0 ^ 64)));
        }
    };
    auto rdB = [&](char* cb, bf16x8 (&bfr)[4][2], int nbase) {
#pragma unroll
        for (int nt = 0; nt < 2; ++nt) {
            const int rb = 32768 + (wc * 64 + (nbase + nt) * 16 + l15) * 128;
            bfr[nbase + nt][0] = __builtin_bit_cast(bf16x8, *(const uint4*)(cb + rb + sl0));
            bfr[nbase + nt][1] = __builtin_bit_cast(bf16x8, *(const uint4*)(cb + rb + (sl0 ^ 64)));
        }
    };
    auto quad = [&](bf16x8 (&afr)[4][2], bf16x8 (&bfr)[4][2], int mb, int nb) {
        __builtin_amdgcn_s_setprio(1);
#pragma unroll
        for (int mt = 0; mt < 4; ++mt)
#pragma unroll
            for (int nt = 0; nt < 2; ++nt)
#pragma unroll
                for (int kk = 0; kk < 2; ++kk)
                    acc[mb + mt][nb + nt] = __builtin_amdgcn_mfma_f32_16x16x32_bf16(
                        afr[mt][kk], bfr[nb + nt][kk], acc[mb + mt][nb + nt], 0, 0, 0);
        __builtin_amdgcn_s_setprio(0);
    };

    // prologue: kt0 (B,A halves) -> lds[0]; kt1 -> lds[1]. 16 issues.
    stage(lds[0], 1, 0, 0);  stage(lds[0], 1, 1, 0);
    stage(lds[0], 0, 0, 0);  stage(lds[0], 0, 1, 0);
    stage(lds[1], 1, 0, 64); stage(lds[1], 1, 1, 64);
    stage(lds[1], 0, 0, 64); stage(lds[1], 0, 1, 64);
    asm volatile("s_waitcnt vmcnt(8)" ::: "memory");   // kt0 resident
    ph_barrier();

    for (int it = 0; it < NI; ++it) {
        const bool st = (it + 1 < NI);
#pragma unroll
        for (int hf = 0; hf < 2; ++hf) {
            char* cb = lds[hf];
            const int kS = (2 * it + 2 + hf) << 6;     // staged K-tile offset
            bf16x8 afr[4][2], bfr[4][2];

            // ---- ph0: B n0-1 + A m0-3 -> MFMA quad (0,0) ---------------
            rdB(cb, bfr, 0);
            rdA(cb, afr, 0);
            quad(afr, bfr, 0, 0);
            ph_barrier();

            // ---- ph1: B n2-3 -> MFMA quad (0,2) ------------------------
            rdB(cb, bfr, 2);
            quad(afr, bfr, 0, 2);
            ph_barrier();

            // ---- ph2: A m4-7; stage next B -> cb; MFMA quad (4,2) ------
            rdA(cb, afr, 4);
            if (st) { stage(cb, 1, 0, kS); stage(cb, 1, 1, kS); }
            quad(afr, bfr, 4, 2);
            ph_barrier();

            // ---- ph3: stage next A -> cb; MFMA quad (4,0) --------------
            if (st) { stage(cb, 0, 0, kS); stage(cb, 0, 1, kS); }
            quad(afr, bfr, 4, 0);
            if (st)
                asm volatile("s_waitcnt vmcnt(8)" ::: "memory");
            else if (hf == 0)
                asm volatile("s_waitcnt vmcnt(0)" ::: "memory");
            ph_barrier();
        }
    }

    // epilogue: C/D layout row=l4*4+reg, col=l15
#pragma unroll
    for (int nt = 0; nt < 4; ++nt) {
        const int colg = n0 + wc * 64 + nt * 16 + l15;
        const float bv = bias[colg];
#pragma unroll
        for (int mt = 0; mt < 8; ++mt) {
            const int rowb = m0 + wr * 128 + mt * 16 + l4 * 4;
#pragma unroll
            for (int r = 0; r < 4; ++r) {
                const float v = acc[mt][nt][r] + bv;
                if (OUT_BF16)
                    ((u16*)Cout)[(size_t)(rowb + r) * N + colg] = f2bf(v);
                else
                    ((float*)Cout)[(size_t)(rowb + r) * N + colg] = v;
            }
        }
    }
}

// ---------------------------------------------------------------------------
// 256x128-tile 8-wave pipelined MFMA GEMM (proj: grid 16x16 = 256 blocks =
// exactly 1 round).  Round-4: relaxed schedule (r2-proven transform) — no
// forced lgkmcnt(0), 2 barriers per K-tile.  Safety: every ds_read has an
// in-phase MFMA consumer, so reads drain before the wave's trailing barrier;
// staged regions are disjoint from in-phase reads (ledger as in r1).
// ---------------------------------------------------------------------------
template <int OUT_BF16>
__global__ __launch_bounds__(512, 2) void gemm_bf16_256(
    const u16* __restrict__ A,    // [M][K] bf16
    const u16* __restrict__ Bt,   // [N][K] bf16 (B transposed)
    const float* __restrict__ bias,
    void* __restrict__ Cout,      // bf16 [M][N] or fp32 [M][N]
    int M, int N, int K)
{
    __shared__ alignas(16) char lds[2][49152];   // [buf][A 32KB | B 16KB]

    const int tid  = threadIdx.x;
    const int lane = tid & 63;
    const int w    = tid >> 6;      // 0..7
    const int wr   = w >> 1;        // 0..3 (M)
    const int wc   = w & 1;         // 0..1 (N)
    const int l15  = lane & 15;
    const int l4   = lane >> 4;
    const int m0   = blockIdx.y * 256;
    const int n0   = blockIdx.x * 128;
    const int NT   = K >> 6;        // K-tiles of 64

    f32x4 acc[4][4] = {};

    const int srow  = w * 16 + (lane >> 3);          // +i*8 per issue
    const int sslot = (lane & 7) ^ (lane >> 3);      // row&7 == lane>>3
    const size_t aoff = (size_t)(m0 + srow) * K + sslot * 8;
    const size_t boff = (size_t)(n0 + srow) * K + sslot * 8;
    const int sdst = w * 2048;

    auto stageA = [&](char* buf, int h, int k0) {
#pragma unroll
        for (int i = 0; i < 2; ++i)
            __builtin_amdgcn_global_load_lds(
                AS1C(A + aoff + (size_t)(h * 128 + i * 8) * K + k0),
                AS3(buf + h * 16384 + sdst + i * 1024), 16, 0, 0);
    };
    auto stageB = [&](char* buf, int k0) {
#pragma unroll
        for (int i = 0; i < 2; ++i)
            __builtin_amdgcn_global_load_lds(
                AS1C(Bt + boff + (size_t)(i * 8) * K + k0),
                AS3(buf + 32768 + sdst + i * 1024), 16, 0, 0);
    };

    stageB(lds[0], 0);
    stageA(lds[0], 0, 0);
    stageA(lds[0], 1, 0);
    stageB(lds[1], 64);
    stageA(lds[1], 0, 64);
    asm volatile("s_waitcnt vmcnt(4)" ::: "memory");
    ph_barrier();

    const int sl0  = (l4 ^ (l15 & 7)) << 4;
    const int sl1  = sl0 ^ 64;
    const int arow = (wr * 32 + l15) * 128;            // within an A-half
    const int brow = 32768 + (wc * 64 + l15) * 128;

    for (int kt = 0; kt < NT; ++kt) {
        char* cb = lds[kt & 1];
        char* nb = lds[(kt & 1) ^ 1];

        // ---- phase 1: read B(8)+Ah0(4), stage (kt+1):Ah1, MFMA m0-1 ------
        bf16x8 bfr[4][2], af[2][2];
#pragma unroll
        for (int nt = 0; nt < 4; ++nt) {
            bfr[nt][0] = __builtin_bit_cast(bf16x8,
                *(const uint4*)(cb + brow + nt * 2048 + sl0));
            bfr[nt][1] = __builtin_bit_cast(bf16x8,
                *(const uint4*)(cb + brow + nt * 2048 + sl1));
        }
#pragma unroll
        for (int mt = 0; mt < 2; ++mt) {
            af[mt][0] = __builtin_bit_cast(bf16x8,
                *(const uint4*)(cb + arow + mt * 2048 + sl0));
            af[mt][1] = __builtin_bit_cast(bf16x8,
                *(const uint4*)(cb + arow + mt * 2048 + sl1));
        }
        if (kt + 1 < NT) stageA(nb, 1, (kt + 1) << 6);   // (kt+1):Ah1
        __builtin_amdgcn_s_setprio(1);
#pragma unroll
        for (int mt = 0; mt < 2; ++mt)
#pragma unroll
            for (int nt = 0; nt < 4; ++nt)
#pragma unroll
                for (int kk = 0; kk < 2; ++kk)
                    acc[mt][nt] = __builtin_amdgcn_mfma_f32_16x16x32_bf16(
                        af[mt][kk], bfr[nt][kk], acc[mt][nt], 0, 0, 0);
        __builtin_amdgcn_s_setprio(0);
        ph_barrier();                       // BARRIER_A

        // ---- phase 2: read Ah1(4), stage (kt+2):{B,Ah0}, MFMA m2-3 -------
        bf16x8 ag[2][2];
#pragma unroll
        for (int mt = 0; mt < 2; ++mt) {
            ag[mt][0] = __builtin_bit_cast(bf16x8,
                *(const uint4*)(cb + 16384 + arow + mt * 2048 + sl0));
            ag[mt][1] = __builtin_bit_cast(bf16x8,
                *(const uint4*)(cb + 16384 + arow + mt * 2048 + sl1));
        }
        if (kt + 2 < NT) {                               // (kt+2):{B,Ah0}
            stageB(cb, (kt + 2) << 6);
            stageA(cb, 0, (kt + 2) << 6);
        }
        __builtin_amdgcn_s_setprio(1);
#pragma unroll
        for (int mt = 0; mt < 2; ++mt)
#pragma unroll
            for (int nt = 0; nt < 4; ++nt)
#pragma unroll
                for (int kk = 0; kk < 2; ++kk)
                    acc[mt + 2][nt] = __builtin_amdgcn_mfma_f32_16x16x32_bf16(
                        ag[mt][kk], bfr[nt][kk], acc[mt + 2][nt], 0, 0, 0);
        __builtin_amdgcn_s_setprio(0);
        if (kt < NT - 2)
            asm volatile("s_waitcnt vmcnt(4)" ::: "memory");
        else
            asm volatile("s_waitcnt vmcnt(0)" ::: "memory");
        ph_barrier();                       // BARRIER_B
    }

    // epilogue: C/D layout row=l4*4+reg, col=l15
#pragma unroll
    for (int nt = 0; nt < 4; ++nt) {
        const int colg = n0 + wc * 64 + nt * 16 + l15;
        const float bv = bias[colg];
#pragma unroll
        for (int mt = 0; mt < 4; ++mt) {
            const int rowb = m0 + (mt < 2 ? wr * 32 + mt * 16
                                          : 128 + wr * 32 + (mt - 2) * 16) + l4 * 4;
#pragma unroll
            for (int r = 0; r < 4; ++r) {
                const float v = acc[mt][nt][r] + bv;
                if (OUT_BF16)
                    ((u16*)Cout)[(size_t)(rowb + r) * N + colg] = f2bf(v);
                else
                    ((float*)Cout)[(size_t)(rowb + r) * N + colg] = v;
            }
        }
    }
}

// ---------------------------------------------------------------------------
// RoPE cos/sin table: ct/st[t][d2], d2 in [0,64).
// ---------------------------------------------------------------------------
__global__ __launch_bounds__(256) void rope_table(
    float* __restrict__ ct, float* __restrict__ st)
{
    const int i = blockIdx.x * 256 + threadIdx.x;   // t*64 + d2
    const int d2 = i & 63, t = i >> 6;
    const float invf = expf(-(float)d2 * (9.210340371976184f / 64.0f));
    const float fr = (float)t * invf;
    ct[i] = cosf(fr);
    st[i] = sinf(fr);
}

// ---------------------------------------------------------------------------
// Fused RoPE + QKV relayout (single pass over qkv):
//   Qc[bh][t][d] = rope(q),  Kc[bh][t][d] = rope(k),  Vt[bh][d][t] = v.
// V path LDS-staged: per-thread column write into vtile, then fully
// coalesced uint4 row-segment stores.
// ---------------------------------------------------------------------------
__global__ __launch_bounds__(256) void rope_kv(
    const u16* __restrict__ qkv, const float* __restrict__ ct,
    const float* __restrict__ st,
    u16* __restrict__ Qc, u16* __restrict__ Kc, u16* __restrict__ Vt)
{
    __shared__ u16 vtile[128][264];      // 264 = 256 + 8 pad (16B-aligned rows)
    const int tid = threadIdx.x;
    const int blk = blockIdx.x;          // b(4) x h(16) x ttile(4)
    const int tt = blk & 3;
    const int h  = (blk >> 2) & 15;
    const int b  = blk >> 6;
    const int t  = tt * 256 + tid;
    const int bh = b * 16 + h;

    const size_t src  = ((size_t)(b * T_SEQ + t)) * QKV_N + h * D_HEAD;
    const size_t dst  = ((size_t)(bh * T_SEQ + t)) * D_HEAD;
    const float* crow = ct + t * 64;
    const float* srow = st + t * 64;

#pragma unroll
    for (int part = 0; part < 2; ++part) {
        const u16* in  = qkv + src + part * C_DIM;
        u16* outp      = (part ? Kc : Qc) + dst;
#pragma unroll
        for (int c = 0; c < 8; ++c) {
            uint4 u1 = *(const uint4*)(in + c * 8);
            uint4 u2 = *(const uint4*)(in + 64 + c * 8);
            float f1[8], f2[8], o1[8], o2[8];
            unpack8(u1, f1); unpack8(u2, f2);
#pragma unroll
            for (int i = 0; i < 8; ++i) {
                const float cv = crow[c * 8 + i], sv = srow[c * 8 + i];
                o1[i] = f1[i] * cv - f2[i] * sv;
                o2[i] = f1[i] * sv + f2[i] * cv;
            }
            *(uint4*)(outp + c * 8)      = pack8(o1);
            *(uint4*)(outp + 64 + c * 8) = pack8(o2);
        }
    }

    // V -> LDS (thread owns column t_local = tid)
#pragma unroll
    for (int c = 0; c < 16; ++c) {
        uint4 v = *(const uint4*)(qkv + src + 2 * C_DIM + c * 8);
        u16 e[8];
        e[0] = (u16)(v.x & 0xffff); e[1] = (u16)(v.x >> 16);
        e[2] = (u16)(v.y & 0xffff); e[3] = (u16)(v.y >> 16);
        e[4] = (u16)(v.z & 0xffff); e[5] = (u16)(v.z >> 16);
        e[6] = (u16)(v.w & 0xffff); e[7] = (u16)(v.w >> 16);
#pragma unroll
        for (int j = 0; j < 8; ++j)
            vtile[c * 8 + j][tid] = e[j];
    }
    __syncthreads();

    // coalesced store: 32 lanes cover one row's 256 u16 (512B contiguous)
    const int dl = tid >> 5;             // 0..7: row within pass
    const int jc = (tid & 31) * 8;       // u16 col
    u16* vt = Vt + ((size_t)bh * D_HEAD) * T_SEQ + (size_t)tt * 256;
#pragma unroll
    for (int pass = 0; pass < 16; ++pass) {
        const int d = pass * 8 + dl;
        *(uint4*)(vt + (size_t)d * T_SEQ + jc) = *(const uint4*)&vtile[d][jc];
    }
}

// ---------------------------------------------------------------------------
// MFMA flash attention, 64-row q-tiles (R6 geometry: 3->2 blocks/CU) with
// DOUBLE-BUFFERED K/V staging: loads for k-tile kt+1 issued right after the
// barrier, in flight across kt's QK/softmax/PV compute. Load-balanced pairing
// (qt = p and 15-p). Fixed-shift softmax P=exp(s-8) (scores ~N(0,1)), single
// end normalization.
// ---------------------------------------------------------------------------
__global__ __launch_bounds__(256) void attn_mfma(
    const u16* __restrict__ Qc,    // [B*H, T, D] roped
    const u16* __restrict__ Kc,    // [B*H, T, D] roped
    const u16* __restrict__ Vt,    // [B*H, D, T]
    u16* __restrict__ y)           // [B, T, C]
{
    __shared__ alignas(16) char KsL[2][16384];   // [cd(16)][row(64)][16B]
    __shared__ alignas(16) char VtsL[2][16384];  // [jc(8)][drow(128)][16B]
    __shared__ alignas(16) char PwL[4][2176];    // per-wave [jc(8)][q(16)][16B]+pad

    const int tid  = threadIdx.x;
    const int lane = tid & 63;
    const int w    = tid >> 6;
    const int l15  = lane & 15;
    const int l4   = lane >> 4;
    const int p    = blockIdx.x;     // 0..7
    const int bh   = blockIdx.y;     // 0..63
    const int h    = bh & 15;
    const int b    = bh >> 4;

    const size_t kbase = (size_t)bh * T_SEQ * D_HEAD;
    const size_t vbase = (size_t)bh * D_HEAD * T_SEQ;
    const float scale = 0.08838834764831845f;   // 1/sqrt(128)
    char* pw = PwL[w];

    for (int half = 0; half < 2; ++half) {
        const int qt = half ? (15 - p) : p;

        // Q fragments (A-layout: m=lane&15, k=(lane>>4)*8+j)
        const int qrow = qt * 64 + w * 16 + l15;
        const u16* qptr = Qc + ((size_t)(bh * T_SEQ + qrow)) * D_HEAD;
        bf16x8 qf[4];
#pragma unroll
        for (int f = 0; f < 4; ++f)
            qf[f] = __builtin_bit_cast(bf16x8, *(const uint4*)(qptr + f * 32 + l4 * 8));

        f32x4 o[8] = {};                 // O[q=l4*4+r][d=db*16+l15]
        float lrow[4] = {};              // per-lane partial denominators

        __syncthreads();   // prior half's readers done before restaging buf 0

        // prologue: stage kt = 0 into buffer 0
        {
            const u16* ksrc = Kc + kbase + (size_t)(0 * 64 + lane) * D_HEAD;
#pragma unroll
            for (int i = 0; i < 4; ++i) {
                const int cd = w * 4 + i;
                __builtin_amdgcn_global_load_lds(AS1C(ksrc + cd * 8),
                                                 AS3(KsL[0] + cd * 1024), 16, 0, 0);
            }
#pragma unroll
            for (int i = 0; i < 4; ++i) {
                const int jc = w + (i >> 1) * 4;
                const int dh = i & 1;
                const u16* vsrc = Vt + vbase + (size_t)(dh * 64 + lane) * T_SEQ
                                  + 0 * 64 + jc * 8;
                __builtin_amdgcn_global_load_lds(AS1C(vsrc),
                                                 AS3(VtsL[0] + jc * 2048 + dh * 1024), 16, 0, 0);
            }
        }

        int buf = 0;
        for (int kt = 0; kt <= qt; ++kt, buf ^= 1) {
            __syncthreads();     // buf visible; buf^1's readers (kt-2) done
            if (kt < qt) {
                const int kn = kt + 1;
                char* kb = KsL[buf ^ 1];
                char* vb = VtsL[buf ^ 1];
                const u16* ksrc = Kc + kbase + (size_t)(kn * 64 + lane) * D_HEAD;
#pragma unroll
                for (int i = 0; i < 4; ++i) {
                    const int cd = w * 4 + i;
                    __builtin_amdgcn_global_load_lds(AS1C(ksrc + cd * 8),
                                                     AS3(kb + cd * 1024), 16, 0, 0);
                }
#pragma unroll
                for (int i = 0; i < 4; ++i) {
                    const int jc = w + (i >> 1) * 4;
                    const int dh = i & 1;
                    const u16* vsrc = Vt + vbase + (size_t)(dh * 64 + lane) * T_SEQ
                                      + kn * 64 + jc * 8;
                    __builtin_amdgcn_global_load_lds(AS1C(vsrc),
                                                     AS3(vb + jc * 2048 + dh * 1024), 16, 0, 0);
                }
            }

            const char* kbuf = KsL[buf];
            const char* vbuf = VtsL[buf];

            // QK^T: 16 MFMAs
            f32x4 sacc[4] = {};
#pragma unroll
            for (int nb = 0; nb < 4; ++nb)
#pragma unroll
                for (int kc = 0; kc < 4; ++kc) {
                    bf16x8 kf = __builtin_bit_cast(bf16x8,
                        *(const uint4*)(kbuf + (kc * 4 + l4) * 1024 + (nb * 16 + l15) * 16));
                    sacc[nb] = __builtin_amdgcn_mfma_f32_16x16x32_bf16(
                        qf[kc], kf, sacc[nb], 0, 0, 0);
                }

            // P = exp(s*scale - 8), causal-masked on diagonal; partial denoms
#pragma unroll
            for (int nb = 0; nb < 4; ++nb)
#pragma unroll
                for (int r = 0; r < 4; ++r) {
                    const bool masked =
                        (kt == qt) && ((nb * 16 + l15) > (w * 16 + l4 * 4 + r));
                    const float e = masked ? 0.f
                        : __expf(sacc[nb][r] * scale - 8.0f);
                    sacc[nb][r] = e;
                    lrow[r] += e;
                }

            // P: C-layout regs -> bf16 -> per-wave LDS in A-layout chunks
#pragma unroll
            for (int nb = 0; nb < 4; ++nb)
#pragma unroll
                for (int r = 0; r < 4; ++r) {
                    const int j = nb * 16 + l15;
                    const int q = l4 * 4 + r;
                    *(u16*)(pw + (j >> 3) * 272 + q * 16 + (j & 7) * 2) =
                        f2bf(sacc[nb][r]);
                }

            // PV: O += P @ V
            bf16x8 pf[2];
#pragma unroll
            for (int kc2 = 0; kc2 < 2; ++kc2)
                pf[kc2] = __builtin_bit_cast(bf16x8,
                    *(const uint4*)(pw + (kc2 * 4 + l4) * 272 + l15 * 16));
#pragma unroll
            for (int db = 0; db < 8; ++db)
#pragma unroll
                for (int kc2 = 0; kc2 < 2; ++kc2) {
                    bf16x8 vf = __builtin_bit_cast(bf16x8,
                        *(const uint4*)(vbuf + (kc2 * 4 + l4) * 2048 + (db * 16 + l15) * 16));
                    o[db] = __builtin_amdgcn_mfma_f32_16x16x32_bf16(
                        pf[kc2], vf, o[db], 0, 0, 0);
                }
        }

        // end-of-row reduce of denominators across the 16 l15 lanes
        float inv[4];
#pragma unroll
        for (int r = 0; r < 4; ++r) {
            float ls = lrow[r];
#pragma unroll
            for (int off = 1; off < 16; off <<= 1)
                ls += __shfl_xor(ls, off, 64);
            inv[r] = 1.f / ls;
        }
#pragma unroll
        for (int db = 0; db < 8; ++db)
#pragma unroll
            for (int r = 0; r < 4; ++r) {
                const int q = qt * 64 + w * 16 + l4 * 4 + r;
                const int d = h * D_HEAD + db * 16 + l15;
                y[(size_t)(b * T_SEQ + q) * C_DIM + d] = f2bf(o[db][r] * inv[r]);
            }
    }
}

// ---------------------------------------------------------------------------
extern "C" void kernel_launch(void* const* d_in, const int* in_sizes, int n_in,
                              void* d_out, int out_size, void* d_ws, size_t ws_size,
                              hipStream_t stream) {
    const float* x      = (const float*)d_in[0];
    const float* w_attn = (const float*)d_in[1];
    const float* b_attn = (const float*)d_in[2];
    const float* w_proj = (const float*)d_in[3];
    const float* b_proj = (const float*)d_in[4];
    float* out = (float*)d_out;

    char* ws = (char*)d_ws;
    u16* xb   = (u16*)(ws);                        // [4096][2048]    16.78 MB
    u16* waT  = (u16*)(ws + 16777216);             // [6144][2048]    25.17 MB
    u16* Qc   = (u16*)(ws);                        // [64][1024][128] 16.78 MB
    u16* Kc   = (u16*)(ws + 16777216);             // [64][1024][128] 16.78 MB
    u16* Vt   = (u16*)(ws + 33554432);             // [64][128][1024] 16.78 MB
    u16* qkvb = (u16*)(ws + 50331648);             // [4096][6144]    50.33 MB
    u16* wpT  = (u16*)(ws + 50331648);             // [2048][2048]     8.39 MB (after rope_kv)
    u16* yb   = (u16*)(ws + 100663296);            // [4096][2048]    16.78 MB
    float* ct = (float*)(ws + 100663296);          // [1024][64] 256 KB (dead before attn)
    float* st = ct + 65536;

    cast_bf16<<<(BT * C_DIM / 4) / 256, 256, 0, stream>>>(x, xb);
    transpose_cast<<<dim3(QKV_N / 32, C_DIM / 32), 256, 0, stream>>>(w_attn, waT, C_DIM, QKV_N);
    rope_table<<<(T_SEQ * 64) / 256, 256, 0, stream>>>(ct, st);

    gemm_bf16_8ph<1><<<dim3(QKV_N / 256, BT / 256), 512, 0, stream>>>(
        xb, waT, b_attn, qkvb, BT, QKV_N, C_DIM);

    rope_kv<<<256, 256, 0, stream>>>(qkvb, ct, st, Qc, Kc, Vt);

    transpose_cast<<<dim3(C_DIM / 32, C_DIM / 32), 256, 0, stream>>>(w_proj, wpT, C_DIM, C_DIM);

    attn_mfma<<<dim3(8, 4 * H_NUM), 256, 0, stream>>>(Qc, Kc, Vt, yb);

    gemm_bf16_256<0><<<dim3(C_DIM / 128, BT / 256), 512, 0, stream>>>(
        yb, wpT, b_proj, out, BT, C_DIM, C_DIM);
}

// Round 5
// 362.649 us; speedup vs baseline: 1.1445x; 1.0879x over previous
//
#include <hip/hip_runtime.h>
#include <math.h>

#define T_SEQ 1024
#define C_DIM 2048
#define H_NUM 16
#define D_HEAD 128
#define BT 4096              // B*T rows
#define QKV_N 6144           // 3*C

typedef __bf16 bf16x8 __attribute__((ext_vector_type(8)));
typedef float f32x4 __attribute__((ext_vector_type(4)));
typedef unsigned short u16;
typedef unsigned int u32;

#define AS1C(p) ((const __attribute__((address_space(1))) void*)(p))
#define AS3(p)  ((__attribute__((address_space(3))) void*)(p))

__device__ __forceinline__ u16 f2bf(float f) {
    u32 u = __builtin_bit_cast(u32, f);
    u += 0x7fffu + ((u >> 16) & 1u);          // RNE
    return (u16)(u >> 16);
}
__device__ __forceinline__ void unpack8(uint4 u, float* f) {
    const u32 w0 = u.x, w1 = u.y, w2 = u.z, w3 = u.w;
    f[0] = __builtin_bit_cast(float, w0 << 16);
    f[1] = __builtin_bit_cast(float, w0 & 0xffff0000u);
    f[2] = __builtin_bit_cast(float, w1 << 16);
    f[3] = __builtin_bit_cast(float, w1 & 0xffff0000u);
    f[4] = __builtin_bit_cast(float, w2 << 16);
    f[5] = __builtin_bit_cast(float, w2 & 0xffff0000u);
    f[6] = __builtin_bit_cast(float, w3 << 16);
    f[7] = __builtin_bit_cast(float, w3 & 0xffff0000u);
}
__device__ __forceinline__ uint4 pack8(const float* f) {
    uint4 u;
    u.x = (u32)f2bf(f[0]) | ((u32)f2bf(f[1]) << 16);
    u.y = (u32)f2bf(f[2]) | ((u32)f2bf(f[3]) << 16);
    u.z = (u32)f2bf(f[4]) | ((u32)f2bf(f[5]) << 16);
    u.w = (u32)f2bf(f[6]) | ((u32)f2bf(f[7]) << 16);
    return u;
}

__device__ __forceinline__ void ph_barrier() {
    asm volatile("" ::: "memory");
    __builtin_amdgcn_s_barrier();
    asm volatile("" ::: "memory");
}

// ---------------------------------------------------------------------------
// Elementwise fp32 -> bf16 cast (x -> xb).
// ---------------------------------------------------------------------------
__global__ __launch_bounds__(256) void cast_bf16(
    const float* __restrict__ in, u16* __restrict__ out)
{
    int i = blockIdx.x * 256 + threadIdx.x;
    float4 v = ((const float4*)in)[i];
    ushort4 o;
    o.x = f2bf(v.x); o.y = f2bf(v.y); o.z = f2bf(v.z); o.w = f2bf(v.w);
    ((ushort4*)out)[i] = o;
}

// ---------------------------------------------------------------------------
// fp32 [R][Cc] -> bf16 [Cc][R] transpose+cast. 32x32 tile, 256 threads.
// ---------------------------------------------------------------------------
__global__ __launch_bounds__(256) void transpose_cast(
    const float* __restrict__ in, u16* __restrict__ out, int R, int Cc)
{
    __shared__ float tile[32][33];
    const int c0 = blockIdx.x * 32, r0 = blockIdx.y * 32;
    const int tx = threadIdx.x & 31, ty = threadIdx.x >> 5;  // ty 0..7
#pragma unroll
    for (int i = 0; i < 32; i += 8)
        tile[ty + i][tx] = in[(size_t)(r0 + ty + i) * Cc + c0 + tx];
    __syncthreads();
#pragma unroll
    for (int i = 0; i < 32; i += 8)
        out[(size_t)(c0 + ty + i) * R + r0 + tx] = f2bf(tile[tx][ty + i]);
}

// ---------------------------------------------------------------------------
// 256x192-tile 8-wave MFMA GEMM for the QKV projection (round-2 verbatim:
// the session's best GEMM — 119.9 us, MfmaUtil 37.6%, grid 32x16 = 512
// blocks = exactly 2 scheduling rounds). 2 relaxed phases per K-tile, no
// forced lgkmcnt, counted vmcnt(5), setprio around MFMA clusters.
// ---------------------------------------------------------------------------
template <int OUT_BF16>
__global__ __launch_bounds__(512, 2) void gemm_bf16_192(
    const u16* __restrict__ A,    // [M][K] bf16
    const u16* __restrict__ Bt,   // [N][K] bf16 (B transposed)
    const float* __restrict__ bias,
    void* __restrict__ Cout,      // bf16 [M][N] or fp32 [M][N]
    int M, int N, int K)
{
    __shared__ alignas(16) char lds[2][57344];   // [Ah0 16K][Ah1 16K][B 24K]

    const int tid  = threadIdx.x;
    const int lane = tid & 63;
    const int w    = tid >> 6;      // 0..7
    const int wr   = w >> 2;        // 0..1 (M)
    const int wc   = w & 3;         // 0..3 (N)
    const int l15  = lane & 15;
    const int l4   = lane >> 4;
    const int m0   = blockIdx.y * 256;
    const int n0   = blockIdx.x * 192;
    const int NT   = K >> 6;        // K-tiles of 64

    f32x4 acc[8][3] = {};

    const int srow  = w * 16 + (lane >> 3);          // A rows, +i*8 per issue
    const int sslot = (lane & 7) ^ (lane >> 3);      // row&7 == lane>>3
    const size_t aoff = (size_t)(m0 + srow) * K + sslot * 8;
    const int brow_s = w * 8 + (lane >> 3);          // B rows, +i*64 per issue
    const size_t boff = (size_t)(n0 + brow_s) * K + sslot * 8;
    const int sdst = w * 2048;

    auto stageA = [&](char* buf, int h, int k0) {    // one 128-row A half
#pragma unroll
        for (int i = 0; i < 2; ++i)
            __builtin_amdgcn_global_load_lds(
                AS1C(A + aoff + (size_t)(h * 128 + i * 8) * K + k0),
                AS3(buf + h * 16384 + sdst + i * 1024), 16, 0, 0);
    };
    auto stageB = [&](char* buf, int k0) {           // 192 B rows, 3 issues
#pragma unroll
        for (int i = 0; i < 3; ++i)
            __builtin_amdgcn_global_load_lds(
                AS1C(Bt + boff + (size_t)(i * 64) * K + k0),
                AS3(buf + 32768 + i * 8192 + w * 1024), 16, 0, 0);
    };

    // prologue: kt0 fully (7 loads) into buf0; kt1 {B,Ah0} (5) into buf1.
    stageB(lds[0], 0);
    stageA(lds[0], 0, 0);
    stageA(lds[0], 1, 0);
    stageB(lds[1], 64);
    stageA(lds[1], 0, 64);
    asm volatile("s_waitcnt vmcnt(5)" ::: "memory");
    __builtin_amdgcn_s_barrier();
    asm volatile("" ::: "memory");

    const int sl0  = (l4 ^ (l15 & 7)) << 4;
    const int sl1  = sl0 ^ 64;
    const int arow = (wr * 64 + l15) * 128;            // within an A-half
    const int brow = 32768 + (wc * 48 + l15) * 128;

    for (int kt = 0; kt < NT; ++kt) {
        char* cb = lds[kt & 1];
        char* nb = lds[(kt & 1) ^ 1];

        // ---- phase 1: read B(6)+Ah0(8), stage (kt+1):Ah1, MFMA mf 0-3 ----
        bf16x8 bfr[3][2], af[4][2];
#pragma unroll
        for (int nt = 0; nt < 3; ++nt) {
            bfr[nt][0] = __builtin_bit_cast(bf16x8,
                *(const uint4*)(cb + brow + nt * 2048 + sl0));
            bfr[nt][1] = __builtin_bit_cast(bf16x8,
                *(const uint4*)(cb + brow + nt * 2048 + sl1));
        }
#pragma unroll
        for (int mt = 0; mt < 4; ++mt) {
            af[mt][0] = __builtin_bit_cast(bf16x8,
                *(const uint4*)(cb + arow + mt * 2048 + sl0));
            af[mt][1] = __builtin_bit_cast(bf16x8,
                *(const uint4*)(cb + arow + mt * 2048 + sl1));
        }
        if (kt + 1 < NT) stageA(nb, 1, (kt + 1) << 6);
        __builtin_amdgcn_s_setprio(1);
#pragma unroll
        for (int mt = 0; mt < 4; ++mt)
#pragma unroll
            for (int nt = 0; nt < 3; ++nt)
#pragma unroll
                for (int kk = 0; kk < 2; ++kk)
                    acc[mt][nt] = __builtin_amdgcn_mfma_f32_16x16x32_bf16(
                        af[mt][kk], bfr[nt][kk], acc[mt][nt], 0, 0, 0);
        __builtin_amdgcn_s_setprio(0);
        __builtin_amdgcn_s_barrier();        // BARRIER_A
        asm volatile("" ::: "memory");

        // ---- phase 2: read Ah1(8), stage (kt+2):{B,Ah0}, MFMA mf 4-7 -----
        bf16x8 ag[4][2];
#pragma unroll
        for (int mt = 0; mt < 4; ++mt) {
            ag[mt][0] = __builtin_bit_cast(bf16x8,
                *(const uint4*)(cb + 16384 + arow + mt * 2048 + sl0));
            ag[mt][1] = __builtin_bit_cast(bf16x8,
                *(const uint4*)(cb + 16384 + arow + mt * 2048 + sl1));
        }
        if (kt + 2 < NT) {
            stageB(cb, (kt + 2) << 6);
            stageA(cb, 0, (kt + 2) << 6);
        }
        __builtin_amdgcn_s_setprio(1);
#pragma unroll
        for (int mt = 0; mt < 4; ++mt)
#pragma unroll
            for (int nt = 0; nt < 3; ++nt)
#pragma unroll
                for (int kk = 0; kk < 2; ++kk)
                    acc[mt + 4][nt] = __builtin_amdgcn_mfma_f32_16x16x32_bf16(
                        ag[mt][kk], bfr[nt][kk], acc[mt + 4][nt], 0, 0, 0);
        __builtin_amdgcn_s_setprio(0);
        if (kt < NT - 2)
            asm volatile("s_waitcnt vmcnt(5)" ::: "memory");
        else
            asm volatile("s_waitcnt vmcnt(0)" ::: "memory");
        __builtin_amdgcn_s_barrier();        // BARRIER_B
        asm volatile("" ::: "memory");
    }

    // epilogue: C/D layout row=l4*4+reg, col=l15
#pragma unroll
    for (int nt = 0; nt < 3; ++nt) {
        const int colg = n0 + wc * 48 + nt * 16 + l15;
        const float bv = bias[colg];
#pragma unroll
        for (int mt = 0; mt < 8; ++mt) {
            const int rowb = m0 + ((mt >> 2) ? 128 : 0) + wr * 64
                           + (mt & 3) * 16 + l4 * 4;
#pragma unroll
            for (int r = 0; r < 4; ++r) {
                const float v = acc[mt][nt][r] + bv;
                if (OUT_BF16)
                    ((u16*)Cout)[(size_t)(rowb + r) * N + colg] = f2bf(v);
                else
                    ((float*)Cout)[(size_t)(rowb + r) * N + colg] = v;
            }
        }
    }
}

// ---------------------------------------------------------------------------
// 256x128-tile 8-wave pipelined MFMA GEMM (proj: grid 16x16 = 256 blocks =
// exactly 1 round). Relaxed schedule, benched r4.
// ---------------------------------------------------------------------------
template <int OUT_BF16>
__global__ __launch_bounds__(512, 2) void gemm_bf16_256(
    const u16* __restrict__ A,    // [M][K] bf16
    const u16* __restrict__ Bt,   // [N][K] bf16 (B transposed)
    const float* __restrict__ bias,
    void* __restrict__ Cout,      // bf16 [M][N] or fp32 [M][N]
    int M, int N, int K)
{
    __shared__ alignas(16) char lds[2][49152];   // [buf][A 32KB | B 16KB]

    const int tid  = threadIdx.x;
    const int lane = tid & 63;
    const int w    = tid >> 6;      // 0..7
    const int wr   = w >> 1;        // 0..3 (M)
    const int wc   = w & 1;         // 0..1 (N)
    const int l15  = lane & 15;
    const int l4   = lane >> 4;
    const int m0   = blockIdx.y * 256;
    const int n0   = blockIdx.x * 128;
    const int NT   = K >> 6;        // K-tiles of 64

    f32x4 acc[4][4] = {};

    const int srow  = w * 16 + (lane >> 3);          // +i*8 per issue
    const int sslot = (lane & 7) ^ (lane >> 3);      // row&7 == lane>>3
    const size_t aoff = (size_t)(m0 + srow) * K + sslot * 8;
    const size_t boff = (size_t)(n0 + srow) * K + sslot * 8;
    const int sdst = w * 2048;

    auto stageA = [&](char* buf, int h, int k0) {
#pragma unroll
        for (int i = 0; i < 2; ++i)
            __builtin_amdgcn_global_load_lds(
                AS1C(A + aoff + (size_t)(h * 128 + i * 8) * K + k0),
                AS3(buf + h * 16384 + sdst + i * 1024), 16, 0, 0);
    };
    auto stageB = [&](char* buf, int k0) {
#pragma unroll
        for (int i = 0; i < 2; ++i)
            __builtin_amdgcn_global_load_lds(
                AS1C(Bt + boff + (size_t)(i * 8) * K + k0),
                AS3(buf + 32768 + sdst + i * 1024), 16, 0, 0);
    };

    stageB(lds[0], 0);
    stageA(lds[0], 0, 0);
    stageA(lds[0], 1, 0);
    stageB(lds[1], 64);
    stageA(lds[1], 0, 64);
    asm volatile("s_waitcnt vmcnt(4)" ::: "memory");
    ph_barrier();

    const int sl0  = (l4 ^ (l15 & 7)) << 4;
    const int sl1  = sl0 ^ 64;
    const int arow = (wr * 32 + l15) * 128;            // within an A-half
    const int brow = 32768 + (wc * 64 + l15) * 128;

    for (int kt = 0; kt < NT; ++kt) {
        char* cb = lds[kt & 1];
        char* nb = lds[(kt & 1) ^ 1];

        // ---- phase 1: read B(8)+Ah0(4), stage (kt+1):Ah1, MFMA m0-1 ------
        bf16x8 bfr[4][2], af[2][2];
#pragma unroll
        for (int nt = 0; nt < 4; ++nt) {
            bfr[nt][0] = __builtin_bit_cast(bf16x8,
                *(const uint4*)(cb + brow + nt * 2048 + sl0));
            bfr[nt][1] = __builtin_bit_cast(bf16x8,
                *(const uint4*)(cb + brow + nt * 2048 + sl1));
        }
#pragma unroll
        for (int mt = 0; mt < 2; ++mt) {
            af[mt][0] = __builtin_bit_cast(bf16x8,
                *(const uint4*)(cb + arow + mt * 2048 + sl0));
            af[mt][1] = __builtin_bit_cast(bf16x8,
                *(const uint4*)(cb + arow + mt * 2048 + sl1));
        }
        if (kt + 1 < NT) stageA(nb, 1, (kt + 1) << 6);   // (kt+1):Ah1
        __builtin_amdgcn_s_setprio(1);
#pragma unroll
        for (int mt = 0; mt < 2; ++mt)
#pragma unroll
            for (int nt = 0; nt < 4; ++nt)
#pragma unroll
                for (int kk = 0; kk < 2; ++kk)
                    acc[mt][nt] = __builtin_amdgcn_mfma_f32_16x16x32_bf16(
                        af[mt][kk], bfr[nt][kk], acc[mt][nt], 0, 0, 0);
        __builtin_amdgcn_s_setprio(0);
        ph_barrier();                       // BARRIER_A

        // ---- phase 2: read Ah1(4), stage (kt+2):{B,Ah0}, MFMA m2-3 -------
        bf16x8 ag[2][2];
#pragma unroll
        for (int mt = 0; mt < 2; ++mt) {
            ag[mt][0] = __builtin_bit_cast(bf16x8,
                *(const uint4*)(cb + 16384 + arow + mt * 2048 + sl0));
            ag[mt][1] = __builtin_bit_cast(bf16x8,
                *(const uint4*)(cb + 16384 + arow + mt * 2048 + sl1));
        }
        if (kt + 2 < NT) {                               // (kt+2):{B,Ah0}
            stageB(cb, (kt + 2) << 6);
            stageA(cb, 0, (kt + 2) << 6);
        }
        __builtin_amdgcn_s_setprio(1);
#pragma unroll
        for (int mt = 0; mt < 2; ++mt)
#pragma unroll
            for (int nt = 0; nt < 4; ++nt)
#pragma unroll
                for (int kk = 0; kk < 2; ++kk)
                    acc[mt + 2][nt] = __builtin_amdgcn_mfma_f32_16x16x32_bf16(
                        ag[mt][kk], bfr[nt][kk], acc[mt + 2][nt], 0, 0, 0);
        __builtin_amdgcn_s_setprio(0);
        if (kt < NT - 2)
            asm volatile("s_waitcnt vmcnt(4)" ::: "memory");
        else
            asm volatile("s_waitcnt vmcnt(0)" ::: "memory");
        ph_barrier();                       // BARRIER_B
    }

    // epilogue: C/D layout row=l4*4+reg, col=l15
#pragma unroll
    for (int nt = 0; nt < 4; ++nt) {
        const int colg = n0 + wc * 64 + nt * 16 + l15;
        const float bv = bias[colg];
#pragma unroll
        for (int mt = 0; mt < 4; ++mt) {
            const int rowb = m0 + (mt < 2 ? wr * 32 + mt * 16
                                          : 128 + wr * 32 + (mt - 2) * 16) + l4 * 4;
#pragma unroll
            for (int r = 0; r < 4; ++r) {
                const float v = acc[mt][nt][r] + bv;
                if (OUT_BF16)
                    ((u16*)Cout)[(size_t)(rowb + r) * N + colg] = f2bf(v);
                else
                    ((float*)Cout)[(size_t)(rowb + r) * N + colg] = v;
            }
        }
    }
}

// ---------------------------------------------------------------------------
// RoPE cos/sin table: ct/st[t][d2], d2 in [0,64).
// ---------------------------------------------------------------------------
__global__ __launch_bounds__(256) void rope_table(
    float* __restrict__ ct, float* __restrict__ st)
{
    const int i = blockIdx.x * 256 + threadIdx.x;   // t*64 + d2
    const int d2 = i & 63, t = i >> 6;
    const float invf = expf(-(float)d2 * (9.210340371976184f / 64.0f));
    const float fr = (float)t * invf;
    ct[i] = cosf(fr);
    st[i] = sinf(fr);
}

// ---------------------------------------------------------------------------
// Fused RoPE + QKV relayout v3.
// Round-5 fix: the old Q/K path read per-lane uint4 at 12 KB lane stride
// (64 cache lines per instruction -> ~4x HBM read amplification on 33 MB).
// New Q/K path: 16-lane groups read 256 B CONTIGUOUS per row; the RoPE pair
// (d2, d2+64) lives in the partner lane (lane^8) -> exchange via 4x
// __shfl_xor, rope entirely in registers, no LDS. Writes are 1 KB contiguous
// per wave.  V path: r4-proven vtile pattern (conflict-free LDS stage +
// coalesced 512 B output rows); its scatter read remains (1/3 of traffic).
// ---------------------------------------------------------------------------
__global__ __launch_bounds__(256) void rope_kv(
    const u16* __restrict__ qkv, const float* __restrict__ ct,
    const float* __restrict__ st,
    u16* __restrict__ Qc, u16* __restrict__ Kc, u16* __restrict__ Vt)
{
    __shared__ u16 vtile[128][264];      // 264 = 256 + 8 pad (16B-aligned rows)
    const int tid = threadIdx.x;
    const int blk = blockIdx.x;          // b(4) x h(16) x ttile(4)
    const int tt = blk & 3;
    const int h  = (blk >> 2) & 15;
    const int b  = blk >> 6;
    const int bh = b * 16 + h;

    // ---------------- Q/K: coalesced reads + shfl rope --------------------
    const int c8 = tid & 15;             // 16B chunk within the 128-d head
    const int rg = tid >> 4;             // row within sweep (16 rows/sweep)
    const float sgn = (c8 < 8) ? -1.f : 1.f;

#pragma unroll 4
    for (int s = 0; s < 16; ++s) {
        const int row = s * 16 + rg;     // 0..255
        const int t   = tt * 256 + row;
        const size_t rsrc = (size_t)(b * T_SEQ + t) * QKV_N + h * D_HEAD;
        const size_t rdst = (size_t)(bh * T_SEQ + t) * D_HEAD + c8 * 8;

        // cos/sin for this thread's 8 cols (d2 = (c8&7)*8 + i)
        const float* crow = ct + t * 64 + (c8 & 7) * 8;
        const float* srow = st + t * 64 + (c8 & 7) * 8;
        float cs[8], sn[8];
        *(float4*)(cs)     = *(const float4*)(crow);
        *(float4*)(cs + 4) = *(const float4*)(crow + 4);
        *(float4*)(sn)     = *(const float4*)(srow);
        *(float4*)(sn + 4) = *(const float4*)(srow + 4);

#pragma unroll
        for (int part = 0; part < 2; ++part) {
            uint4 u = *(const uint4*)(qkv + rsrc + part * C_DIM + c8 * 8);
            uint4 pu;
            pu.x = (u32)__shfl_xor((int)u.x, 8, 64);
            pu.y = (u32)__shfl_xor((int)u.y, 8, 64);
            pu.z = (u32)__shfl_xor((int)u.z, 8, 64);
            pu.w = (u32)__shfl_xor((int)u.w, 8, 64);
            float f[8], pf[8], o[8];
            unpack8(u, f); unpack8(pu, pf);
#pragma unroll
            for (int i = 0; i < 8; ++i)
                o[i] = f[i] * cs[i] + sgn * pf[i] * sn[i];
            u16* outp = (part ? Kc : Qc) + rdst;
            *(uint4*)outp = pack8(o);
        }
    }

    // ---------------- V: column stage + coalesced out (r4 pattern) --------
    const int t = tt * 256 + tid;
    const size_t vsrc = (size_t)(b * T_SEQ + t) * QKV_N + 2 * C_DIM + h * D_HEAD;
#pragma unroll
    for (int c = 0; c < 16; ++c) {
        uint4 v = *(const uint4*)(qkv + vsrc + c * 8);
        u16 e[8];
        e[0] = (u16)(v.x & 0xffff); e[1] = (u16)(v.x >> 16);
        e[2] = (u16)(v.y & 0xffff); e[3] = (u16)(v.y >> 16);
        e[4] = (u16)(v.z & 0xffff); e[5] = (u16)(v.z >> 16);
        e[6] = (u16)(v.w & 0xffff); e[7] = (u16)(v.w >> 16);
#pragma unroll
        for (int j = 0; j < 8; ++j)
            vtile[c * 8 + j][tid] = e[j];
    }
    __syncthreads();

    // coalesced store: 32 lanes cover one row's 256 u16 (512B contiguous)
    const int dl = tid >> 5;             // 0..7: row within pass
    const int jc = (tid & 31) * 8;       // u16 col
    u16* vt = Vt + ((size_t)bh * D_HEAD) * T_SEQ + (size_t)tt * 256;
#pragma unroll
    for (int pass = 0; pass < 16; ++pass) {
        const int d = pass * 8 + dl;
        *(uint4*)(vt + (size_t)d * T_SEQ + jc) = *(const uint4*)&vtile[d][jc];
    }
}

// ---------------------------------------------------------------------------
// MFMA flash attention, 64-row q-tiles (unchanged this round).
// ---------------------------------------------------------------------------
__global__ __launch_bounds__(256) void attn_mfma(
    const u16* __restrict__ Qc,    // [B*H, T, D] roped
    const u16* __restrict__ Kc,    // [B*H, T, D] roped
    const u16* __restrict__ Vt,    // [B*H, D, T]
    u16* __restrict__ y)           // [B, T, C]
{
    __shared__ alignas(16) char KsL[2][16384];   // [cd(16)][row(64)][16B]
    __shared__ alignas(16) char VtsL[2][16384];  // [jc(8)][drow(128)][16B]
    __shared__ alignas(16) char PwL[4][2176];    // per-wave [jc(8)][q(16)][16B]+pad

    const int tid  = threadIdx.x;
    const int lane = tid & 63;
    const int w    = tid >> 6;
    const int l15  = lane & 15;
    const int l4   = lane >> 4;
    const int p    = blockIdx.x;     // 0..7
    const int bh   = blockIdx.y;     // 0..63
    const int h    = bh & 15;
    const int b    = bh >> 4;

    const size_t kbase = (size_t)bh * T_SEQ * D_HEAD;
    const size_t vbase = (size_t)bh * D_HEAD * T_SEQ;
    const float scale = 0.08838834764831845f;   // 1/sqrt(128)
    char* pw = PwL[w];

    for (int half = 0; half < 2; ++half) {
        const int qt = half ? (15 - p) : p;

        // Q fragments (A-layout: m=lane&15, k=(lane>>4)*8+j)
        const int qrow = qt * 64 + w * 16 + l15;
        const u16* qptr = Qc + ((size_t)(bh * T_SEQ + qrow)) * D_HEAD;
        bf16x8 qf[4];
#pragma unroll
        for (int f = 0; f < 4; ++f)
            qf[f] = __builtin_bit_cast(bf16x8, *(const uint4*)(qptr + f * 32 + l4 * 8));

        f32x4 o[8] = {};                 // O[q=l4*4+r][d=db*16+l15]
        float lrow[4] = {};              // per-lane partial denominators

        __syncthreads();   // prior half's readers done before restaging buf 0

        // prologue: stage kt = 0 into buffer 0
        {
            const u16* ksrc = Kc + kbase + (size_t)(0 * 64 + lane) * D_HEAD;
#pragma unroll
            for (int i = 0; i < 4; ++i) {
                const int cd = w * 4 + i;
                __builtin_amdgcn_global_load_lds(AS1C(ksrc + cd * 8),
                                                 AS3(KsL[0] + cd * 1024), 16, 0, 0);
            }
#pragma unroll
            for (int i = 0; i < 4; ++i) {
                const int jc = w + (i >> 1) * 4;
                const int dh = i & 1;
                const u16* vsrc = Vt + vbase + (size_t)(dh * 64 + lane) * T_SEQ
                                  + 0 * 64 + jc * 8;
                __builtin_amdgcn_global_load_lds(AS1C(vsrc),
                                                 AS3(VtsL[0] + jc * 2048 + dh * 1024), 16, 0, 0);
            }
        }

        int buf = 0;
        for (int kt = 0; kt <= qt; ++kt, buf ^= 1) {
            __syncthreads();     // buf visible; buf^1's readers (kt-2) done
            if (kt < qt) {
                const int kn = kt + 1;
                char* kb = KsL[buf ^ 1];
                char* vb = VtsL[buf ^ 1];
                const u16* ksrc = Kc + kbase + (size_t)(kn * 64 + lane) * D_HEAD;
#pragma unroll
                for (int i = 0; i < 4; ++i) {
                    const int cd = w * 4 + i;
                    __builtin_amdgcn_global_load_lds(AS1C(ksrc + cd * 8),
                                                     AS3(kb + cd * 1024), 16, 0, 0);
                }
#pragma unroll
                for (int i = 0; i < 4; ++i) {
                    const int jc = w + (i >> 1) * 4;
                    const int dh = i & 1;
                    const u16* vsrc = Vt + vbase + (size_t)(dh * 64 + lane) * T_SEQ
                                      + kn * 64 + jc * 8;
                    __builtin_amdgcn_global_load_lds(AS1C(vsrc),
                                                     AS3(vb + jc * 2048 + dh * 1024), 16, 0, 0);
                }
            }

            const char* kbuf = KsL[buf];
            const char* vbuf = VtsL[buf];

            // QK^T: 16 MFMAs
            f32x4 sacc[4] = {};
#pragma unroll
            for (int nb = 0; nb < 4; ++nb)
#pragma unroll
                for (int kc = 0; kc < 4; ++kc) {
                    bf16x8 kf = __builtin_bit_cast(bf16x8,
                        *(const uint4*)(kbuf + (kc * 4 + l4) * 1024 + (nb * 16 + l15) * 16));
                    sacc[nb] = __builtin_amdgcn_mfma_f32_16x16x32_bf16(
                        qf[kc], kf, sacc[nb], 0, 0, 0);
                }

            // P = exp(s*scale - 8), causal-masked on diagonal; partial denoms
#pragma unroll
            for (int nb = 0; nb < 4; ++nb)
#pragma unroll
                for (int r = 0; r < 4; ++r) {
                    const bool masked =
                        (kt == qt) && ((nb * 16 + l15) > (w * 16 + l4 * 4 + r));
                    const float e = masked ? 0.f
                        : __expf(sacc[nb][r] * scale - 8.0f);
                    sacc[nb][r] = e;
                    lrow[r] += e;
                }

            // P: C-layout regs -> bf16 -> per-wave LDS in A-layout chunks
#pragma unroll
            for (int nb = 0; nb < 4; ++nb)
#pragma unroll
                for (int r = 0; r < 4; ++r) {
                    const int j = nb * 16 + l15;
                    const int q = l4 * 4 + r;
                    *(u16*)(pw + (j >> 3) * 272 + q * 16 + (j & 7) * 2) =
                        f2bf(sacc[nb][r]);
                }

            // PV: O += P @ V
            bf16x8 pf[2];
#pragma unroll
            for (int kc2 = 0; kc2 < 2; ++kc2)
                pf[kc2] = __builtin_bit_cast(bf16x8,
                    *(const uint4*)(pw + (kc2 * 4 + l4) * 272 + l15 * 16));
#pragma unroll
            for (int db = 0; db < 8; ++db)
#pragma unroll
                for (int kc2 = 0; kc2 < 2; ++kc2) {
                    bf16x8 vf = __builtin_bit_cast(bf16x8,
                        *(const uint4*)(vbuf + (kc2 * 4 + l4) * 2048 + (db * 16 + l15) * 16));
                    o[db] = __builtin_amdgcn_mfma_f32_16x16x32_bf16(
                        pf[kc2], vf, o[db], 0, 0, 0);
                }
        }

        // end-of-row reduce of denominators across the 16 l15 lanes
        float inv[4];
#pragma unroll
        for (int r = 0; r < 4; ++r) {
            float ls = lrow[r];
#pragma unroll
            for (int off = 1; off < 16; off <<= 1)
                ls += __shfl_xor(ls, off, 64);
            inv[r] = 1.f / ls;
        }
#pragma unroll
        for (int db = 0; db < 8; ++db)
#pragma unroll
            for (int r = 0; r < 4; ++r) {
                const int q = qt * 64 + w * 16 + l4 * 4 + r;
                const int d = h * D_HEAD + db * 16 + l15;
                y[(size_t)(b * T_SEQ + q) * C_DIM + d] = f2bf(o[db][r] * inv[r]);
            }
    }
}

// ---------------------------------------------------------------------------
extern "C" void kernel_launch(void* const* d_in, const int* in_sizes, int n_in,
                              void* d_out, int out_size, void* d_ws, size_t ws_size,
                              hipStream_t stream) {
    const float* x      = (const float*)d_in[0];
    const float* w_attn = (const float*)d_in[1];
    const float* b_attn = (const float*)d_in[2];
    const float* w_proj = (const float*)d_in[3];
    const float* b_proj = (const float*)d_in[4];
    float* out = (float*)d_out;

    char* ws = (char*)d_ws;
    u16* xb   = (u16*)(ws);                        // [4096][2048]    16.78 MB
    u16* waT  = (u16*)(ws + 16777216);             // [6144][2048]    25.17 MB
    u16* Qc   = (u16*)(ws);                        // [64][1024][128] 16.78 MB
    u16* Kc   = (u16*)(ws + 16777216);             // [64][1024][128] 16.78 MB
    u16* Vt   = (u16*)(ws + 33554432);             // [64][128][1024] 16.78 MB
    u16* qkvb = (u16*)(ws + 50331648);             // [4096][6144]    50.33 MB
    u16* wpT  = (u16*)(ws + 50331648);             // [2048][2048]     8.39 MB (after rope_kv)
    u16* yb   = (u16*)(ws + 100663296);            // [4096][2048]    16.78 MB
    float* ct = (float*)(ws + 100663296);          // [1024][64] 256 KB (dead before attn)
    float* st = ct + 65536;

    cast_bf16<<<(BT * C_DIM / 4) / 256, 256, 0, stream>>>(x, xb);
    transpose_cast<<<dim3(QKV_N / 32, C_DIM / 32), 256, 0, stream>>>(w_attn, waT, C_DIM, QKV_N);
    rope_table<<<(T_SEQ * 64) / 256, 256, 0, stream>>>(ct, st);

    gemm_bf16_192<1><<<dim3(QKV_N / 192, BT / 256), 512, 0, stream>>>(
        xb, waT, b_attn, qkvb, BT, QKV_N, C_DIM);

    rope_kv<<<256, 256, 0, stream>>>(qkvb, ct, st, Qc, Kc, Vt);

    transpose_cast<<<dim3(C_DIM / 32, C_DIM / 32), 256, 0, stream>>>(w_proj, wpT, C_DIM, C_DIM);

    attn_mfma<<<dim3(8, 4 * H_NUM), 256, 0, stream>>>(Qc, Kc, Vt, yb);

    gemm_bf16_256<0><<<dim3(C_DIM / 128, BT / 256), 512, 0, stream>>>(
        yb, wpT, b_proj, out, BT, C_DIM, C_DIM);
}

// Round 6
// 351.227 us; speedup vs baseline: 1.1817x; 1.0325x over previous
//
#include <hip/hip_runtime.h>
#include <math.h>

#define T_SEQ 1024
#define C_DIM 2048
#define H_NUM 16
#define D_HEAD 128
#define BT 4096              // B*T rows
#define QKV_N 6144           // 3*C

typedef __bf16 bf16x8 __attribute__((ext_vector_type(8)));
typedef float f32x4 __attribute__((ext_vector_type(4)));
typedef unsigned short u16;
typedef unsigned int u32;

#define AS1C(p) ((const __attribute__((address_space(1))) void*)(p))
#define AS3(p)  ((__attribute__((address_space(3))) void*)(p))

__device__ __forceinline__ u16 f2bf(float f) {
    u32 u = __builtin_bit_cast(u32, f);
    u += 0x7fffu + ((u >> 16) & 1u);          // RNE
    return (u16)(u >> 16);
}
__device__ __forceinline__ void unpack8(uint4 u, float* f) {
    const u32 w0 = u.x, w1 = u.y, w2 = u.z, w3 = u.w;
    f[0] = __builtin_bit_cast(float, w0 << 16);
    f[1] = __builtin_bit_cast(float, w0 & 0xffff0000u);
    f[2] = __builtin_bit_cast(float, w1 << 16);
    f[3] = __builtin_bit_cast(float, w1 & 0xffff0000u);
    f[4] = __builtin_bit_cast(float, w2 << 16);
    f[5] = __builtin_bit_cast(float, w2 & 0xffff0000u);
    f[6] = __builtin_bit_cast(float, w3 << 16);
    f[7] = __builtin_bit_cast(float, w3 & 0xffff0000u);
}
__device__ __forceinline__ uint4 pack8(const float* f) {
    uint4 u;
    u.x = (u32)f2bf(f[0]) | ((u32)f2bf(f[1]) << 16);
    u.y = (u32)f2bf(f[2]) | ((u32)f2bf(f[3]) << 16);
    u.z = (u32)f2bf(f[4]) | ((u32)f2bf(f[5]) << 16);
    u.w = (u32)f2bf(f[6]) | ((u32)f2bf(f[7]) << 16);
    return u;
}

__device__ __forceinline__ void ph_barrier() {
    asm volatile("" ::: "memory");
    __builtin_amdgcn_s_barrier();
    asm volatile("" ::: "memory");
}

// ---------------------------------------------------------------------------
// Elementwise fp32 -> bf16 cast (x -> xb).
// ---------------------------------------------------------------------------
__global__ __launch_bounds__(256) void cast_bf16(
    const float* __restrict__ in, u16* __restrict__ out)
{
    int i = blockIdx.x * 256 + threadIdx.x;
    float4 v = ((const float4*)in)[i];
    ushort4 o;
    o.x = f2bf(v.x); o.y = f2bf(v.y); o.z = f2bf(v.z); o.w = f2bf(v.w);
    ((ushort4*)out)[i] = o;
}

// ---------------------------------------------------------------------------
// fp32 [R][Cc] -> bf16 [Cc][R] transpose+cast. 32x32 tile, 256 threads.
// ---------------------------------------------------------------------------
__global__ __launch_bounds__(256) void transpose_cast(
    const float* __restrict__ in, u16* __restrict__ out, int R, int Cc)
{
    __shared__ float tile[32][33];
    const int c0 = blockIdx.x * 32, r0 = blockIdx.y * 32;
    const int tx = threadIdx.x & 31, ty = threadIdx.x >> 5;  // ty 0..7
#pragma unroll
    for (int i = 0; i < 32; i += 8)
        tile[ty + i][tx] = in[(size_t)(r0 + ty + i) * Cc + c0 + tx];
    __syncthreads();
#pragma unroll
    for (int i = 0; i < 32; i += 8)
        out[(size_t)(c0 + ty + i) * R + r0 + tx] = f2bf(tile[tx][ty + i]);
}

// ---------------------------------------------------------------------------
// 128xBN-tile 8-wave MFMA GEMM, TWO BLOCKS PER CU (round-6 experiment).
// r5 counters: the 1-block/CU 256x192 kernel sits at its SERIAL floor
// (3994 cy/ktile = MFMA 2367 + LDS 1375 + 250): lockstep waves never overlap
// the MFMA and LDS pipes. Halving BM to 128 halves LDS (80KB for BN=192,
// 64KB for BN=128) so 2 blocks co-reside per CU; one block's LDS/staging
// phase co-schedules against the other's MFMA phase (m114 mechanism) with
// NO intra-block schedule change: same r2-proven 2-phase relaxed schedule,
// same rule-21 swizzle (0 conflicts r1-r5), same counted-vmcnt discipline.
// Geometry: BK=64; waves 2M x 4N; per-wave 64 x BN/4 = 4 m-frags x NTW
// n-frags (NTW = BN/64). Grids: QKV 32x32=1024 blocks = 2 resident rounds;
// proj 16x32=512 = exactly 1 resident round. 100% makespan both.
// vmcnt ledger (per wave; A stages 2 issues, B stages BI=BN/64):
//   ph1 reads cb.{B, A mt01}; stage (kt+1):A -> nb   [nb.A readers done
//       at (kt-1) BARRIER_B];  MFMA mt01; BARRIER_A [all cb.B reads done:
//       each has in-phase MFMA consumer].
//   ph2 reads cb.A mt23; stage (kt+2):B -> cb.B [disjoint from A reads;
//       B reads done at BARRIER_A]; MFMA mt23;
//       end-of-kt FIFO = [B(kt+1):BI, A(kt+1):2, B(kt+2):BI] ->
//       vmcnt(BI) drains kt+1 fully, leaves B(kt+2) in flight.
//       Tail: kt==NT-2 -> vmcnt(0) (no B(kt+2) staged). BARRIER_B.
// ---------------------------------------------------------------------------
template <int BN, int OUT_BF16>
__global__ __launch_bounds__(512, 4) void gemm_bf16_ov(
    const u16* __restrict__ A,    // [M][K] bf16
    const u16* __restrict__ Bt,   // [N][K] bf16 (B transposed)
    const float* __restrict__ bias,
    void* __restrict__ Cout,      // bf16 [M][N] or fp32 [M][N]
    int M, int N, int K)
{
    constexpr int BI  = BN / 64;         // B stage issues per wave
    constexpr int NTW = BN / 64;         // n-frags per wave
    constexpr int WCOLS = BN / 4;        // cols per wave
    __shared__ alignas(16) char lds[2][16384 + BN * 128];  // [buf][A 16K | B]

    const int tid  = threadIdx.x;
    const int lane = tid & 63;
    const int w    = tid >> 6;      // 0..7
    const int wr   = w >> 2;        // 0..1 (M)
    const int wc   = w & 3;         // 0..3 (N)
    const int l15  = lane & 15;
    const int l4   = lane >> 4;
    const int m0   = blockIdx.y * 128;
    const int n0   = blockIdx.x * BN;
    const int NT   = K >> 6;        // K-tiles of 64

    f32x4 acc[4][NTW] = {};

    // staging: linear gload_lds dest + pre-XOR'd global source (rule 21)
    const int srow  = w * 16 + (lane >> 3);          // A rows, +i*8 per issue
    const int sslot = (lane & 7) ^ (lane >> 3);      // row&7 == lane>>3
    const size_t aoff = (size_t)(m0 + srow) * K + sslot * 8;
    const int brow_s = w * 8 + (lane >> 3);          // B rows, +i*64 per issue
    const size_t boff = (size_t)(n0 + brow_s) * K + sslot * 8;

    auto stageA = [&](char* buf, int k0) {           // 128 rows, 2 issues
#pragma unroll
        for (int i = 0; i < 2; ++i)
            __builtin_amdgcn_global_load_lds(
                AS1C(A + aoff + (size_t)(i * 8) * K + k0),
                AS3(buf + w * 2048 + i * 1024), 16, 0, 0);
    };
    auto stageB = [&](char* buf, int k0) {           // BN rows, BI issues
#pragma unroll
        for (int i = 0; i < BI; ++i)
            __builtin_amdgcn_global_load_lds(
                AS1C(Bt + boff + (size_t)(i * 64) * K + k0),
                AS3(buf + 16384 + i * 8192 + w * 1024), 16, 0, 0);
    };

    // prologue: B(kt0), A(kt0) -> buf0; B(kt1) -> buf1.
    stageB(lds[0], 0);
    stageA(lds[0], 0);
    stageB(lds[1], 64);
    if (BI == 3) asm volatile("s_waitcnt vmcnt(3)" ::: "memory");
    else         asm volatile("s_waitcnt vmcnt(2)" ::: "memory");
    ph_barrier();

    const int sl0  = (l4 ^ (l15 & 7)) << 4;
    const int sl1  = sl0 ^ 64;
    const int arow = (wr * 64 + l15) * 128;
    const int brow = 16384 + (wc * WCOLS + l15) * 128;

    for (int kt = 0; kt < NT; ++kt) {
        char* cb = lds[kt & 1];
        char* nb = lds[(kt & 1) ^ 1];

        // ---- phase 1: read B(all)+A mt01, stage (kt+1):A, MFMA mt01 ------
        bf16x8 bfr[NTW][2], af[2][2];
#pragma unroll
        for (int nt = 0; nt < NTW; ++nt) {
            bfr[nt][0] = __builtin_bit_cast(bf16x8,
                *(const uint4*)(cb + brow + nt * 2048 + sl0));
            bfr[nt][1] = __builtin_bit_cast(bf16x8,
                *(const uint4*)(cb + brow + nt * 2048 + sl1));
        }
#pragma unroll
        for (int mt = 0; mt < 2; ++mt) {
            af[mt][0] = __builtin_bit_cast(bf16x8,
                *(const uint4*)(cb + arow + mt * 2048 + sl0));
            af[mt][1] = __builtin_bit_cast(bf16x8,
                *(const uint4*)(cb + arow + mt * 2048 + sl1));
        }
        if (kt + 1 < NT) stageA(nb, (kt + 1) << 6);
        __builtin_amdgcn_s_setprio(1);
#pragma unroll
        for (int mt = 0; mt < 2; ++mt)
#pragma unroll
            for (int nt = 0; nt < NTW; ++nt)
#pragma unroll
                for (int kk = 0; kk < 2; ++kk)
                    acc[mt][nt] = __builtin_amdgcn_mfma_f32_16x16x32_bf16(
                        af[mt][kk], bfr[nt][kk], acc[mt][nt], 0, 0, 0);
        __builtin_amdgcn_s_setprio(0);
        ph_barrier();                       // BARRIER_A

        // ---- phase 2: read A mt23, stage (kt+2):B -> cb, MFMA mt23 -------
        bf16x8 ag[2][2];
#pragma unroll
        for (int mt = 0; mt < 2; ++mt) {
            ag[mt][0] = __builtin_bit_cast(bf16x8,
                *(const uint4*)(cb + arow + (2 + mt) * 2048 + sl0));
            ag[mt][1] = __builtin_bit_cast(bf16x8,
                *(const uint4*)(cb + arow + (2 + mt) * 2048 + sl1));
        }
        if (kt + 2 < NT) stageB(cb, (kt + 2) << 6);
        __builtin_amdgcn_s_setprio(1);
#pragma unroll
        for (int mt = 0; mt < 2; ++mt)
#pragma unroll
            for (int nt = 0; nt < NTW; ++nt)
#pragma unroll
                for (int kk = 0; kk < 2; ++kk)
                    acc[mt + 2][nt] = __builtin_amdgcn_mfma_f32_16x16x32_bf16(
                        ag[mt][kk], bfr[nt][kk], acc[mt + 2][nt], 0, 0, 0);
        __builtin_amdgcn_s_setprio(0);
        if (kt < NT - 2) {
            if (BI == 3) asm volatile("s_waitcnt vmcnt(3)" ::: "memory");
            else         asm volatile("s_waitcnt vmcnt(2)" ::: "memory");
        } else {
            asm volatile("s_waitcnt vmcnt(0)" ::: "memory");
        }
        ph_barrier();                       // BARRIER_B
    }

    // epilogue: C/D layout row=l4*4+reg, col=l15
#pragma unroll
    for (int nt = 0; nt < NTW; ++nt) {
        const int colg = n0 + wc * WCOLS + nt * 16 + l15;
        const float bv = bias[colg];
#pragma unroll
        for (int mt = 0; mt < 4; ++mt) {
            const int rowb = m0 + wr * 64 + mt * 16 + l4 * 4;
#pragma unroll
            for (int r = 0; r < 4; ++r) {
                const float v = acc[mt][nt][r] + bv;
                if (OUT_BF16)
                    ((u16*)Cout)[(size_t)(rowb + r) * N + colg] = f2bf(v);
                else
                    ((float*)Cout)[(size_t)(rowb + r) * N + colg] = v;
            }
        }
    }
}

// ---------------------------------------------------------------------------
// RoPE cos/sin table: ct/st[t][d2], d2 in [0,64).
// ---------------------------------------------------------------------------
__global__ __launch_bounds__(256) void rope_table(
    float* __restrict__ ct, float* __restrict__ st)
{
    const int i = blockIdx.x * 256 + threadIdx.x;   // t*64 + d2
    const int d2 = i & 63, t = i >> 6;
    const float invf = expf(-(float)d2 * (9.210340371976184f / 64.0f));
    const float fr = (float)t * invf;
    ct[i] = cosf(fr);
    st[i] = sinf(fr);
}

// ---------------------------------------------------------------------------
// Fused RoPE + QKV relayout v3 (round-5 proven).
// ---------------------------------------------------------------------------
__global__ __launch_bounds__(256) void rope_kv(
    const u16* __restrict__ qkv, const float* __restrict__ ct,
    const float* __restrict__ st,
    u16* __restrict__ Qc, u16* __restrict__ Kc, u16* __restrict__ Vt)
{
    __shared__ u16 vtile[128][264];      // 264 = 256 + 8 pad (16B-aligned rows)
    const int tid = threadIdx.x;
    const int blk = blockIdx.x;          // b(4) x h(16) x ttile(4)
    const int tt = blk & 3;
    const int h  = (blk >> 2) & 15;
    const int b  = blk >> 6;
    const int bh = b * 16 + h;

    // ---------------- Q/K: coalesced reads + shfl rope --------------------
    const int c8 = tid & 15;             // 16B chunk within the 128-d head
    const int rg = tid >> 4;             // row within sweep (16 rows/sweep)
    const float sgn = (c8 < 8) ? -1.f : 1.f;

#pragma unroll 4
    for (int s = 0; s < 16; ++s) {
        const int row = s * 16 + rg;     // 0..255
        const int t   = tt * 256 + row;
        const size_t rsrc = (size_t)(b * T_SEQ + t) * QKV_N + h * D_HEAD;
        const size_t rdst = (size_t)(bh * T_SEQ + t) * D_HEAD + c8 * 8;

        // cos/sin for this thread's 8 cols (d2 = (c8&7)*8 + i)
        const float* crow = ct + t * 64 + (c8 & 7) * 8;
        const float* srow = st + t * 64 + (c8 & 7) * 8;
        float cs[8], sn[8];
        *(float4*)(cs)     = *(const float4*)(crow);
        *(float4*)(cs + 4) = *(const float4*)(crow + 4);
        *(float4*)(sn)     = *(const float4*)(srow);
        *(float4*)(sn + 4) = *(const float4*)(srow + 4);

#pragma unroll
        for (int part = 0; part < 2; ++part) {
            uint4 u = *(const uint4*)(qkv + rsrc + part * C_DIM + c8 * 8);
            uint4 pu;
            pu.x = (u32)__shfl_xor((int)u.x, 8, 64);
            pu.y = (u32)__shfl_xor((int)u.y, 8, 64);
            pu.z = (u32)__shfl_xor((int)u.z, 8, 64);
            pu.w = (u32)__shfl_xor((int)u.w, 8, 64);
            float f[8], pf[8], o[8];
            unpack8(u, f); unpack8(pu, pf);
#pragma unroll
            for (int i = 0; i < 8; ++i)
                o[i] = f[i] * cs[i] + sgn * pf[i] * sn[i];
            u16* outp = (part ? Kc : Qc) + rdst;
            *(uint4*)outp = pack8(o);
        }
    }

    // ---------------- V: column stage + coalesced out ---------------------
    const int t = tt * 256 + tid;
    const size_t vsrc = (size_t)(b * T_SEQ + t) * QKV_N + 2 * C_DIM + h * D_HEAD;
#pragma unroll
    for (int c = 0; c < 16; ++c) {
        uint4 v = *(const uint4*)(qkv + vsrc + c * 8);
        u16 e[8];
        e[0] = (u16)(v.x & 0xffff); e[1] = (u16)(v.x >> 16);
        e[2] = (u16)(v.y & 0xffff); e[3] = (u16)(v.y >> 16);
        e[4] = (u16)(v.z & 0xffff); e[5] = (u16)(v.z >> 16);
        e[6] = (u16)(v.w & 0xffff); e[7] = (u16)(v.w >> 16);
#pragma unroll
        for (int j = 0; j < 8; ++j)
            vtile[c * 8 + j][tid] = e[j];
    }
    __syncthreads();

    // coalesced store: 32 lanes cover one row's 256 u16 (512B contiguous)
    const int dl = tid >> 5;             // 0..7: row within pass
    const int jc = (tid & 31) * 8;       // u16 col
    u16* vt = Vt + ((size_t)bh * D_HEAD) * T_SEQ + (size_t)tt * 256;
#pragma unroll
    for (int pass = 0; pass < 16; ++pass) {
        const int d = pass * 8 + dl;
        *(uint4*)(vt + (size_t)d * T_SEQ + jc) = *(const uint4*)&vtile[d][jc];
    }
}

// ---------------------------------------------------------------------------
// MFMA flash attention, 64-row q-tiles (unchanged this round).
// ---------------------------------------------------------------------------
__global__ __launch_bounds__(256) void attn_mfma(
    const u16* __restrict__ Qc,    // [B*H, T, D] roped
    const u16* __restrict__ Kc,    // [B*H, T, D] roped
    const u16* __restrict__ Vt,    // [B*H, D, T]
    u16* __restrict__ y)           // [B, T, C]
{
    __shared__ alignas(16) char KsL[2][16384];   // [cd(16)][row(64)][16B]
    __shared__ alignas(16) char VtsL[2][16384];  // [jc(8)][drow(128)][16B]
    __shared__ alignas(16) char PwL[4][2176];    // per-wave [jc(8)][q(16)][16B]+pad

    const int tid  = threadIdx.x;
    const int lane = tid & 63;
    const int w    = tid >> 6;
    const int l15  = lane & 15;
    const int l4   = lane >> 4;
    const int p    = blockIdx.x;     // 0..7
    const int bh   = blockIdx.y;     // 0..63
    const int h    = bh & 15;
    const int b    = bh >> 4;

    const size_t kbase = (size_t)bh * T_SEQ * D_HEAD;
    const size_t vbase = (size_t)bh * D_HEAD * T_SEQ;
    const float scale = 0.08838834764831845f;   // 1/sqrt(128)
    char* pw = PwL[w];

    for (int half = 0; half < 2; ++half) {
        const int qt = half ? (15 - p) : p;

        // Q fragments (A-layout: m=lane&15, k=(lane>>4)*8+j)
        const int qrow = qt * 64 + w * 16 + l15;
        const u16* qptr = Qc + ((size_t)(bh * T_SEQ + qrow)) * D_HEAD;
        bf16x8 qf[4];
#pragma unroll
        for (int f = 0; f < 4; ++f)
            qf[f] = __builtin_bit_cast(bf16x8, *(const uint4*)(qptr + f * 32 + l4 * 8));

        f32x4 o[8] = {};                 // O[q=l4*4+r][d=db*16+l15]
        float lrow[4] = {};              // per-lane partial denominators

        __syncthreads();   // prior half's readers done before restaging buf 0

        // prologue: stage kt = 0 into buffer 0
        {
            const u16* ksrc = Kc + kbase + (size_t)(0 * 64 + lane) * D_HEAD;
#pragma unroll
            for (int i = 0; i < 4; ++i) {
                const int cd = w * 4 + i;
                __builtin_amdgcn_global_load_lds(AS1C(ksrc + cd * 8),
                                                 AS3(KsL[0] + cd * 1024), 16, 0, 0);
            }
#pragma unroll
            for (int i = 0; i < 4; ++i) {
                const int jc = w + (i >> 1) * 4;
                const int dh = i & 1;
                const u16* vsrc = Vt + vbase + (size_t)(dh * 64 + lane) * T_SEQ
                                  + 0 * 64 + jc * 8;
                __builtin_amdgcn_global_load_lds(AS1C(vsrc),
                                                 AS3(VtsL[0] + jc * 2048 + dh * 1024), 16, 0, 0);
            }
        }

        int buf = 0;
        for (int kt = 0; kt <= qt; ++kt, buf ^= 1) {
            __syncthreads();     // buf visible; buf^1's readers (kt-2) done
            if (kt < qt) {
                const int kn = kt + 1;
                char* kb = KsL[buf ^ 1];
                char* vb = VtsL[buf ^ 1];
                const u16* ksrc = Kc + kbase + (size_t)(kn * 64 + lane) * D_HEAD;
#pragma unroll
                for (int i = 0; i < 4; ++i) {
                    const int cd = w * 4 + i;
                    __builtin_amdgcn_global_load_lds(AS1C(ksrc + cd * 8),
                                                     AS3(kb + cd * 1024), 16, 0, 0);
                }
#pragma unroll
                for (int i = 0; i < 4; ++i) {
                    const int jc = w + (i >> 1) * 4;
                    const int dh = i & 1;
                    const u16* vsrc = Vt + vbase + (size_t)(dh * 64 + lane) * T_SEQ
                                      + kn * 64 + jc * 8;
                    __builtin_amdgcn_global_load_lds(AS1C(vsrc),
                                                     AS3(vb + jc * 2048 + dh * 1024), 16, 0, 0);
                }
            }

            const char* kbuf = KsL[buf];
            const char* vbuf = VtsL[buf];

            // QK^T: 16 MFMAs
            f32x4 sacc[4] = {};
#pragma unroll
            for (int nb = 0; nb < 4; ++nb)
#pragma unroll
                for (int kc = 0; kc < 4; ++kc) {
                    bf16x8 kf = __builtin_bit_cast(bf16x8,
                        *(const uint4*)(kbuf + (kc * 4 + l4) * 1024 + (nb * 16 + l15) * 16));
                    sacc[nb] = __builtin_amdgcn_mfma_f32_16x16x32_bf16(
                        qf[kc], kf, sacc[nb], 0, 0, 0);
                }

            // P = exp(s*scale - 8), causal-masked on diagonal; partial denoms
#pragma unroll
            for (int nb = 0; nb < 4; ++nb)
#pragma unroll
                for (int r = 0; r < 4; ++r) {
                    const bool masked =
                        (kt == qt) && ((nb * 16 + l15) > (w * 16 + l4 * 4 + r));
                    const float e = masked ? 0.f
                        : __expf(sacc[nb][r] * scale - 8.0f);
                    sacc[nb][r] = e;
                    lrow[r] += e;
                }

            // P: C-layout regs -> bf16 -> per-wave LDS in A-layout chunks
#pragma unroll
            for (int nb = 0; nb < 4; ++nb)
#pragma unroll
                for (int r = 0; r < 4; ++r) {
                    const int j = nb * 16 + l15;
                    const int q = l4 * 4 + r;
                    *(u16*)(pw + (j >> 3) * 272 + q * 16 + (j & 7) * 2) =
                        f2bf(sacc[nb][r]);
                }

            // PV: O += P @ V
            bf16x8 pf[2];
#pragma unroll
            for (int kc2 = 0; kc2 < 2; ++kc2)
                pf[kc2] = __builtin_bit_cast(bf16x8,
                    *(const uint4*)(pw + (kc2 * 4 + l4) * 272 + l15 * 16));
#pragma unroll
            for (int db = 0; db < 8; ++db)
#pragma unroll
                for (int kc2 = 0; kc2 < 2; ++kc2) {
                    bf16x8 vf = __builtin_bit_cast(bf16x8,
                        *(const uint4*)(vbuf + (kc2 * 4 + l4) * 2048 + (db * 16 + l15) * 16));
                    o[db] = __builtin_amdgcn_mfma_f32_16x16x32_bf16(
                        pf[kc2], vf, o[db], 0, 0, 0);
                }
        }

        // end-of-row reduce of denominators across the 16 l15 lanes
        float inv[4];
#pragma unroll
        for (int r = 0; r < 4; ++r) {
            float ls = lrow[r];
#pragma unroll
            for (int off = 1; off < 16; off <<= 1)
                ls += __shfl_xor(ls, off, 64);
            inv[r] = 1.f / ls;
        }
#pragma unroll
        for (int db = 0; db < 8; ++db)
#pragma unroll
            for (int r = 0; r < 4; ++r) {
                const int q = qt * 64 + w * 16 + l4 * 4 + r;
                const int d = h * D_HEAD + db * 16 + l15;
                y[(size_t)(b * T_SEQ + q) * C_DIM + d] = f2bf(o[db][r] * inv[r]);
            }
    }
}

// ---------------------------------------------------------------------------
extern "C" void kernel_launch(void* const* d_in, const int* in_sizes, int n_in,
                              void* d_out, int out_size, void* d_ws, size_t ws_size,
                              hipStream_t stream) {
    const float* x      = (const float*)d_in[0];
    const float* w_attn = (const float*)d_in[1];
    const float* b_attn = (const float*)d_in[2];
    const float* w_proj = (const float*)d_in[3];
    const float* b_proj = (const float*)d_in[4];
    float* out = (float*)d_out;

    char* ws = (char*)d_ws;
    u16* xb   = (u16*)(ws);                        // [4096][2048]    16.78 MB
    u16* waT  = (u16*)(ws + 16777216);             // [6144][2048]    25.17 MB
    u16* Qc   = (u16*)(ws);                        // [64][1024][128] 16.78 MB
    u16* Kc   = (u16*)(ws + 16777216);             // [64][1024][128] 16.78 MB
    u16* Vt   = (u16*)(ws + 33554432);             // [64][128][1024] 16.78 MB
    u16* qkvb = (u16*)(ws + 50331648);             // [4096][6144]    50.33 MB
    u16* wpT  = (u16*)(ws + 50331648);             // [2048][2048]     8.39 MB (after rope_kv)
    u16* yb   = (u16*)(ws + 100663296);            // [4096][2048]    16.78 MB
    float* ct = (float*)(ws + 100663296);          // [1024][64] 256 KB (dead before attn)
    float* st = ct + 65536;

    cast_bf16<<<(BT * C_DIM / 4) / 256, 256, 0, stream>>>(x, xb);
    transpose_cast<<<dim3(QKV_N / 32, C_DIM / 32), 256, 0, stream>>>(w_attn, waT, C_DIM, QKV_N);
    rope_table<<<(T_SEQ * 64) / 256, 256, 0, stream>>>(ct, st);

    gemm_bf16_ov<192, 1><<<dim3(QKV_N / 192, BT / 128), 512, 0, stream>>>(
        xb, waT, b_attn, qkvb, BT, QKV_N, C_DIM);

    rope_kv<<<256, 256, 0, stream>>>(qkvb, ct, st, Qc, Kc, Vt);

    transpose_cast<<<dim3(C_DIM / 32, C_DIM / 32), 256, 0, stream>>>(w_proj, wpT, C_DIM, C_DIM);

    attn_mfma<<<dim3(8, 4 * H_NUM), 256, 0, stream>>>(Qc, Kc, Vt, yb);

    gemm_bf16_ov<128, 0><<<dim3(C_DIM / 128, BT / 128), 512, 0, stream>>>(
        yb, wpT, b_proj, out, BT, C_DIM, C_DIM);
}